// Round 4
// baseline (2623.728 us; speedup 1.0000x reference)
//
#include <hip/hip_runtime.h>

typedef unsigned short u16;
typedef __attribute__((ext_vector_type(8))) short s16x8;
typedef __attribute__((ext_vector_type(8))) unsigned short u16x8;
typedef __attribute__((ext_vector_type(4))) float f32x4;

#define DEV static __device__ __forceinline__
#define MFMA __builtin_amdgcn_mfma_f32_16x16x32_bf16

DEV float bf2f(u16 u) { return __uint_as_float(((unsigned)u) << 16); }
DEV u16 f2bf(float f) {
    unsigned u = __float_as_uint(f);
    return (u16)((u + 0x7FFFu + ((u >> 16) & 1u)) >> 16);
}
DEV void split2(float v, u16& hi, u16& lo) {
    hi = f2bf(v);
    lo = f2bf(v - bf2f(hi));
}

// ---------------------------------------------------------------------------
// GEMM, ALL fp32 I/O: C[M,N] = act( A[M,K] @ B^T + bias[N] ).
// A and B are fp32 in HBM; staged into LDS as (hi,lo) bf16 splits; 3-term
// split MFMA (hi*hi + lo*hi + hi*lo) gives ~1e-6 relative error.
// 64x64 tile / 256 threads / 4 waves (each 32x32 via 2x2 mfma 16x16x32).
// B layout: [N,K] (b_kn=0, ldb=K) or [K,N] (b_kn=1, ldb=N, transposed during
// staging). Optional expert-indexed B/bias, A-row gather, C-row scatter.
// ---------------------------------------------------------------------------
__global__ __launch_bounds__(256) void gemm_f(
    const float* __restrict__ A, int lda,
    const float* __restrict__ Bw, int ldb, long b_estride, int b_kn,
    const float* __restrict__ bias, int bias_estride,
    float* __restrict__ C, int ldc,
    int K, int act,
    const int* __restrict__ perm_in,
    const int* __restrict__ perm_out,
    const int* __restrict__ tile_expert)
{
    __shared__ u16 Ah[64 * 40], Al[64 * 40];
    __shared__ u16 Bh[64 * 40], Bl[64 * 40];
    const int mt = blockIdx.x, nt = blockIdx.y;
    int e = 0;
    if (tile_expert) { e = tile_expert[mt]; if (e < 0) return; }
    const int tid = threadIdx.x, lane = tid & 63, w = tid >> 6;
    const int wr = (w >> 1) * 32, wc = (w & 1) * 32;
    const int quad = lane >> 4, l15 = lane & 15;

    const float* Bbase = Bw + (long)e * b_estride;

    const int r1 = tid >> 2, c8 = (tid & 3) * 8;   // 64 rows x 32 k per tile
    long arow; bool avalid = true;
    if (perm_in) { int p = perm_in[mt * 64 + r1]; avalid = p >= 0; arow = p < 0 ? 0 : p; }
    else arow = (long)mt * 64 + r1;
    const float* Ap = A + arow * (long)lda + c8;

    f32x4 acc[2][2] = {};

    for (int k0 = 0; k0 < K; k0 += 32) {
        __syncthreads();
        {   // A tile: row r1, k = k0+c8 .. +8
            float va[8] = {};
            if (avalid) {
                float4 f0 = *(const float4*)(Ap + k0);
                float4 f1 = *(const float4*)(Ap + k0 + 4);
                va[0] = f0.x; va[1] = f0.y; va[2] = f0.z; va[3] = f0.w;
                va[4] = f1.x; va[5] = f1.y; va[6] = f1.z; va[7] = f1.w;
            }
            u16x8 h8, l8;
            for (int i = 0; i < 8; ++i) { u16 hh, ll; split2(va[i], hh, ll); h8[i] = hh; l8[i] = ll; }
            *(u16x8*)&Ah[r1 * 40 + c8] = h8;
            *(u16x8*)&Al[r1 * 40 + c8] = l8;
        }
        if (b_kn) {   // B[K,N]: load 8 n-consecutive, transpose into [n][k]
            const int kr = tid >> 3, nc = (tid & 7) * 8;
            const float* bp = Bbase + (long)(k0 + kr) * ldb + nt * 64 + nc;
            float4 f0 = *(const float4*)(bp);
            float4 f1 = *(const float4*)(bp + 4);
            float vb[8] = {f0.x, f0.y, f0.z, f0.w, f1.x, f1.y, f1.z, f1.w};
            for (int i = 0; i < 8; ++i) {
                u16 hh, ll; split2(vb[i], hh, ll);
                Bh[(nc + i) * 40 + kr] = hh;
                Bl[(nc + i) * 40 + kr] = ll;
            }
        } else {      // B[N,K]: row nt*64+r1, k = k0+c8 .. +8
            const float* bp = Bbase + ((long)nt * 64 + r1) * ldb + k0 + c8;
            float4 f0 = *(const float4*)(bp);
            float4 f1 = *(const float4*)(bp + 4);
            float vb[8] = {f0.x, f0.y, f0.z, f0.w, f1.x, f1.y, f1.z, f1.w};
            u16x8 h8, l8;
            for (int i = 0; i < 8; ++i) { u16 hh, ll; split2(vb[i], hh, ll); h8[i] = hh; l8[i] = ll; }
            *(u16x8*)&Bh[r1 * 40 + c8] = h8;
            *(u16x8*)&Bl[r1 * 40 + c8] = l8;
        }
        __syncthreads();
        s16x8 ah0 = *(const s16x8*)&Ah[(wr + l15) * 40 + quad * 8];
        s16x8 ah1 = *(const s16x8*)&Ah[(wr + 16 + l15) * 40 + quad * 8];
        s16x8 al0 = *(const s16x8*)&Al[(wr + l15) * 40 + quad * 8];
        s16x8 al1 = *(const s16x8*)&Al[(wr + 16 + l15) * 40 + quad * 8];
        s16x8 bh0 = *(const s16x8*)&Bh[(wc + l15) * 40 + quad * 8];
        s16x8 bh1 = *(const s16x8*)&Bh[(wc + 16 + l15) * 40 + quad * 8];
        s16x8 bl0 = *(const s16x8*)&Bl[(wc + l15) * 40 + quad * 8];
        s16x8 bl1 = *(const s16x8*)&Bl[(wc + 16 + l15) * 40 + quad * 8];
        acc[0][0] = MFMA(ah0, bh0, acc[0][0], 0, 0, 0);
        acc[0][0] = MFMA(al0, bh0, acc[0][0], 0, 0, 0);
        acc[0][0] = MFMA(ah0, bl0, acc[0][0], 0, 0, 0);
        acc[0][1] = MFMA(ah0, bh1, acc[0][1], 0, 0, 0);
        acc[0][1] = MFMA(al0, bh1, acc[0][1], 0, 0, 0);
        acc[0][1] = MFMA(ah0, bl1, acc[0][1], 0, 0, 0);
        acc[1][0] = MFMA(ah1, bh0, acc[1][0], 0, 0, 0);
        acc[1][0] = MFMA(al1, bh0, acc[1][0], 0, 0, 0);
        acc[1][0] = MFMA(ah1, bl0, acc[1][0], 0, 0, 0);
        acc[1][1] = MFMA(ah1, bh1, acc[1][1], 0, 0, 0);
        acc[1][1] = MFMA(al1, bh1, acc[1][1], 0, 0, 0);
        acc[1][1] = MFMA(ah1, bl1, acc[1][1], 0, 0, 0);
    }

    const float* bp = bias + (long)e * bias_estride + nt * 64;
    for (int mi = 0; mi < 2; ++mi) {
        for (int r = 0; r < 4; ++r) {
            const int rloc = wr + mi * 16 + quad * 4 + r;  // C/D: row=(lane>>4)*4+reg
            long orow;
            if (perm_out) { int po = perm_out[mt * 64 + rloc]; if (po < 0) continue; orow = po; }
            else orow = (long)mt * 64 + rloc;
            float* crow = C + orow * (long)ldc + (long)nt * 64;
            for (int ni = 0; ni < 2; ++ni) {
                const int col = wc + ni * 16 + l15;        // C/D: col=lane&15
                float v = acc[mi][ni][r] + bp[col];
                if (act == 1) v = 0.5f * v * (1.f + erff(v * 0.7071067811865475f));
                crow[col] = v;
            }
        }
    }
}

// ---------------------------------------------------------------------------
// Flash attention over ONE batch slice, fp32 in/out, split-bf16 MFMA
// (3-term). Block = 64 Q rows of one head; wave = 16 rows; 32-key tiles.
// V transposed + split during LDS staging. Online softmax in log2 units.
// ---------------------------------------------------------------------------
__global__ __launch_bounds__(256) void attn_f(
    const float* __restrict__ Q, const float* __restrict__ K,
    const float* __restrict__ V, float* __restrict__ O,
    int LK, float sc)
{
    __shared__ u16 Khs[32 * 72], Kls[32 * 72];
    __shared__ u16 Vhs[64 * 40], Vls[64 * 40];
    __shared__ float Ss[4 * 16 * 36];
    const int h = blockIdx.y, qt = blockIdx.x;
    const int tid = threadIdx.x, lane = tid & 63, w = tid >> 6;
    const int quad = lane >> 4, l15 = lane & 15;

    const float* qrow = Q + ((long)qt * 64 + w * 16 + l15) * 512 + h * 64;
    s16x8 qh0, ql0, qh1, ql1;
    {
        float4 f0 = *(const float4*)(qrow + quad * 8);
        float4 f1 = *(const float4*)(qrow + quad * 8 + 4);
        float4 f2 = *(const float4*)(qrow + 32 + quad * 8);
        float4 f3 = *(const float4*)(qrow + 32 + quad * 8 + 4);
        float a[8] = {f0.x, f0.y, f0.z, f0.w, f1.x, f1.y, f1.z, f1.w};
        float c[8] = {f2.x, f2.y, f2.z, f2.w, f3.x, f3.y, f3.z, f3.w};
        for (int i = 0; i < 8; ++i) {
            u16 hh, ll;
            split2(a[i], hh, ll); qh0[i] = (short)hh; ql0[i] = (short)ll;
            split2(c[i], hh, ll); qh1[i] = (short)hh; ql1[i] = (short)ll;
        }
    }

    const int kr = tid >> 3, kc = (tid & 7) * 8;       // K stage: 32 keys x 64 dims
    const int vkey = tid & 31, vhd0 = (tid >> 5) * 8;  // V stage: transpose

    float m_run = -1e30f, l_run = 0.f;
    f32x4 oacc[4] = {};
    float* Sw = &Ss[w * 16 * 36];

    const int ntile = LK >> 5;
    for (int t = 0; t < ntile; ++t) {
        __syncthreads();
        {   // K tile -> Khs/Kls [key][dim]
            const float* kp = K + ((long)t * 32 + kr) * 512 + h * 64 + kc;
            float4 f0 = *(const float4*)(kp);
            float4 f1 = *(const float4*)(kp + 4);
            float a[8] = {f0.x, f0.y, f0.z, f0.w, f1.x, f1.y, f1.z, f1.w};
            u16x8 h8, l8;
            for (int i = 0; i < 8; ++i) { u16 hh, ll; split2(a[i], hh, ll); h8[i] = hh; l8[i] = ll; }
            *(u16x8*)&Khs[kr * 72 + kc] = h8;
            *(u16x8*)&Kls[kr * 72 + kc] = l8;
        }
        {   // V tile -> Vhs/Vls [dim][key] (transposed)
            const float* vp = V + ((long)t * 32 + vkey) * 512 + h * 64 + vhd0;
            float4 f0 = *(const float4*)(vp);
            float4 f1 = *(const float4*)(vp + 4);
            float a[8] = {f0.x, f0.y, f0.z, f0.w, f1.x, f1.y, f1.z, f1.w};
            for (int i = 0; i < 8; ++i) {
                u16 hh, ll; split2(a[i], hh, ll);
                Vhs[(vhd0 + i) * 40 + vkey] = hh;
                Vls[(vhd0 + i) * 40 + vkey] = ll;
            }
        }
        __syncthreads();
        f32x4 s0 = {0.f, 0.f, 0.f, 0.f}, s1 = {0.f, 0.f, 0.f, 0.f};
        {
            s16x8 kh00 = *(const s16x8*)&Khs[l15 * 72 + quad * 8];
            s16x8 kl00 = *(const s16x8*)&Kls[l15 * 72 + quad * 8];
            s16x8 kh01 = *(const s16x8*)&Khs[l15 * 72 + 32 + quad * 8];
            s16x8 kl01 = *(const s16x8*)&Kls[l15 * 72 + 32 + quad * 8];
            s0 = MFMA(qh0, kh00, s0, 0, 0, 0);
            s0 = MFMA(ql0, kh00, s0, 0, 0, 0);
            s0 = MFMA(qh0, kl00, s0, 0, 0, 0);
            s0 = MFMA(qh1, kh01, s0, 0, 0, 0);
            s0 = MFMA(ql1, kh01, s0, 0, 0, 0);
            s0 = MFMA(qh1, kl01, s0, 0, 0, 0);
            s16x8 kh10 = *(const s16x8*)&Khs[(16 + l15) * 72 + quad * 8];
            s16x8 kl10 = *(const s16x8*)&Kls[(16 + l15) * 72 + quad * 8];
            s16x8 kh11 = *(const s16x8*)&Khs[(16 + l15) * 72 + 32 + quad * 8];
            s16x8 kl11 = *(const s16x8*)&Kls[(16 + l15) * 72 + 32 + quad * 8];
            s1 = MFMA(qh0, kh10, s1, 0, 0, 0);
            s1 = MFMA(ql0, kh10, s1, 0, 0, 0);
            s1 = MFMA(qh0, kl10, s1, 0, 0, 0);
            s1 = MFMA(qh1, kh11, s1, 0, 0, 0);
            s1 = MFMA(ql1, kh11, s1, 0, 0, 0);
            s1 = MFMA(qh1, kl11, s1, 0, 0, 0);
        }
        for (int r = 0; r < 4; ++r) {   // C layout: row q = quad*4+r, col key = l15
            Sw[(quad * 4 + r) * 36 + l15]      = s0[r];
            Sw[(quad * 4 + r) * 36 + 16 + l15] = s1[r];
        }
        __syncthreads();
        // A layout: q = l15, keys = quad*8 + j
        float p[8]; float lm = -1e30f;
        const float* srow = &Sw[l15 * 36 + quad * 8];
        for (int j = 0; j < 8; ++j) { p[j] = srow[j] * sc; lm = fmaxf(lm, p[j]); }
        lm = fmaxf(lm, __shfl_xor(lm, 16));
        lm = fmaxf(lm, __shfl_xor(lm, 32));
        const float m_new = fmaxf(m_run, lm);
        const float alpha = exp2f(m_run - m_new);
        float ts = 0.f;
        for (int j = 0; j < 8; ++j) { p[j] = exp2f(p[j] - m_new); ts += p[j]; }
        ts += __shfl_xor(ts, 16);
        ts += __shfl_xor(ts, 32);
        l_run = l_run * alpha + ts;
        m_run = m_new;
        s16x8 ph, pl;
        for (int j = 0; j < 8; ++j) {
            u16 hh, ll; split2(p[j], hh, ll);
            ph[j] = (short)hh; pl[j] = (short)ll;
        }
        float ar[4];
        for (int r = 0; r < 4; ++r) ar[r] = __shfl(alpha, quad * 4 + r);
        for (int tt = 0; tt < 4; ++tt) {
            f32x4 oa = oacc[tt];
            oa[0] *= ar[0]; oa[1] *= ar[1]; oa[2] *= ar[2]; oa[3] *= ar[3];
            s16x8 vh = *(const s16x8*)&Vhs[(tt * 16 + l15) * 40 + quad * 8];
            s16x8 vl = *(const s16x8*)&Vls[(tt * 16 + l15) * 40 + quad * 8];
            oa = MFMA(ph, vh, oa, 0, 0, 0);
            oa = MFMA(pl, vh, oa, 0, 0, 0);
            oa = MFMA(ph, vl, oa, 0, 0, 0);
            oacc[tt] = oa;
        }
    }
    float linv[4];
    for (int r = 0; r < 4; ++r) linv[r] = 1.f / fmaxf(__shfl(l_run, quad * 4 + r), 1e-35f);
    float* obase = O + ((long)qt * 64 + w * 16 + quad * 4) * 512 + h * 64;
    for (int tt = 0; tt < 4; ++tt)
        for (int r = 0; r < 4; ++r)
            obase[(long)r * 512 + tt * 16 + l15] = oacc[tt][r] * linv[r];
}

// ---------------------------------------------------------------------------
// Residual + LayerNorm over D=512, all fp32. One wave per row.
// ---------------------------------------------------------------------------
__global__ __launch_bounds__(256) void ln_f(
    const float* __restrict__ a, const float* __restrict__ bres,
    const float* __restrict__ g, const float* __restrict__ be,
    float* __restrict__ out)
{
    const int tid = threadIdx.x, lane = tid & 63, w = tid >> 6;
    const long row = (long)blockIdx.x * 4 + w;
    const long base = row * 512 + lane * 8;
    float v[8];
    {
        float4 f0 = *(const float4*)(a + base);
        float4 f1 = *(const float4*)(a + base + 4);
        float4 g0 = *(const float4*)(bres + base);
        float4 g1 = *(const float4*)(bres + base + 4);
        v[0] = f0.x + g0.x; v[1] = f0.y + g0.y; v[2] = f0.z + g0.z; v[3] = f0.w + g0.w;
        v[4] = f1.x + g1.x; v[5] = f1.y + g1.y; v[6] = f1.z + g1.z; v[7] = f1.w + g1.w;
    }
    float s = 0.f, sq = 0.f;
    for (int j = 0; j < 8; ++j) { s += v[j]; sq += v[j] * v[j]; }
    for (int m = 1; m < 64; m <<= 1) { s += __shfl_xor(s, m); sq += __shfl_xor(sq, m); }
    const float mu = s * (1.f / 512.f);
    const float var = fmaxf(sq * (1.f / 512.f) - mu * mu, 0.f);
    const float rs = rsqrtf(var + 1e-5f);
    float4 ga = *(const float4*)(g + lane * 8);
    float4 gb = *(const float4*)(g + lane * 8 + 4);
    float4 ba = *(const float4*)(be + lane * 8);
    float4 bb = *(const float4*)(be + lane * 8 + 4);
    float gg[8] = {ga.x, ga.y, ga.z, ga.w, gb.x, gb.y, gb.z, gb.w};
    float bbv[8] = {ba.x, ba.y, ba.z, ba.w, bb.x, bb.y, bb.z, bb.w};
    float o[8];
    for (int j = 0; j < 8; ++j) o[j] = (v[j] - mu) * rs * gg[j] + bbv[j];
    *(float4*)(out + base)     = make_float4(o[0], o[1], o[2], o[3]);
    *(float4*)(out + base + 4) = make_float4(o[4], o[5], o[6], o[7]);
}

// ---------------------------------------------------------------------------
// MoE routing (argmax of logits == argmax of softmax). One wave / token.
// ---------------------------------------------------------------------------
__global__ __launch_bounds__(256) void route_f(
    const float* __restrict__ x, const float* __restrict__ gw, const float* __restrict__ gb,
    int* __restrict__ idx, int* __restrict__ counts)
{
    const int tid = threadIdx.x, lane = tid & 63, w = tid >> 6;
    const long row = (long)blockIdx.x * 4 + w;
    const float* xr = x + row * 512 + lane * 8;
    float4 f0 = *(const float4*)(xr);
    float4 f1 = *(const float4*)(xr + 4);
    float xf[8] = {f0.x, f0.y, f0.z, f0.w, f1.x, f1.y, f1.z, f1.w};
    float best = -1e30f; int bi = 0;
    for (int e = 0; e < 4; ++e) {
        float4 w0 = *(const float4*)(gw + e * 512 + lane * 8);
        float4 w1 = *(const float4*)(gw + e * 512 + lane * 8 + 4);
        float wf[8] = {w0.x, w0.y, w0.z, w0.w, w1.x, w1.y, w1.z, w1.w};
        float d = 0.f;
        for (int j = 0; j < 8; ++j) d += xf[j] * wf[j];
        for (int m = 1; m < 64; m <<= 1) d += __shfl_xor(d, m);
        d += gb[e];
        if (d > best) { best = d; bi = e; }  // strict > keeps first index on tie
    }
    if (lane == 0) { idx[row] = bi; atomicAdd(&counts[bi], 1); }
}

__global__ void plan_k(const int* __restrict__ counts, int* __restrict__ cursors,
                       int* __restrict__ tile_expert)
{
    if (threadIdx.x != 0 || blockIdx.x != 0) return;
    int off = 0;
    for (int e = 0; e < 4; ++e) {
        cursors[e] = off;
        int nt = (counts[e] + 63) >> 6;
        int t0 = off >> 6;
        for (int i = 0; i < nt; ++i) tile_expert[t0 + i] = e;
        off += nt << 6;
    }
    for (int t = off >> 6; t < 132; ++t) tile_expert[t] = -1;
}

__global__ __launch_bounds__(256) void scatter_k(
    const int* __restrict__ idx, int* __restrict__ cursors, int* __restrict__ perm)
{
    const int t = blockIdx.x * 256 + threadIdx.x;
    const int e = idx[t];
    const int pos = atomicAdd(&cursors[e], 1);
    perm[pos] = t;
}

// ---------------------------------------------------------------------------
extern "C" void kernel_launch(void* const* d_in, const int* in_sizes, int n_in,
                              void* d_out, int out_size, void* d_ws, size_t ws_size,
                              hipStream_t stream)
{
    (void)in_sizes; (void)n_in; (void)out_size; (void)ws_size;
    // ALL inputs are fp32 per the reference (jnp.float32); output fp32.
    const float* x        = (const float*)d_in[0];
    const float* mem      = (const float*)d_in[1];
    const float* sa_in_w  = (const float*)d_in[2];
    const float* sa_in_b  = (const float*)d_in[3];
    const float* sa_out_w = (const float*)d_in[4];
    const float* sa_out_b = (const float*)d_in[5];
    const float* ca_in_w  = (const float*)d_in[6];
    const float* ca_in_b  = (const float*)d_in[7];
    const float* ca_out_w = (const float*)d_in[8];
    const float* ca_out_b = (const float*)d_in[9];
    const float* gate_w   = (const float*)d_in[10];
    const float* gate_b   = (const float*)d_in[11];
    const float* w1       = (const float*)d_in[12];
    const float* b1       = (const float*)d_in[13];
    const float* w2       = (const float*)d_in[14];
    const float* b2       = (const float*)d_in[15];
    const float* ln1_g    = (const float*)d_in[16];
    const float* ln1_b    = (const float*)d_in[17];
    const float* ln2_g    = (const float*)d_in[18];
    const float* ln2_b    = (const float*)d_in[19];
    const float* ln3_g    = (const float*)d_in[20];
    const float* ln3_b    = (const float*)d_in[21];

    // ws <= 48.1 MB: three 16 MB fp32 regions + metadata.
    // P0: attnO(self) -> attnO(cross) -> x2
    // P1: per-batch {Q,K,V} (12 MB) -> proj1 -> per-batch qkv -> proj2 -> H chunk
    // P2: x1 -> ymoe
    char* ws = (char*)d_ws;
    float* P0 = (float*)(ws);
    float* P1 = (float*)(ws + 16777216L);
    float* P2 = (float*)(ws + 33554432L);
    int* idx    = (int*)(ws + 50331648L);
    int* perm   = (int*)(ws + 50331648L + 32768);
    int* counts = (int*)(ws + 50331648L + 32768 + 33792);
    int* cursors= (int*)(ws + 50331648L + 32768 + 33792 + 16);
    int* tile_e = (int*)(ws + 50331648L + 32768 + 33792 + 32);

    const float sc = 0.125f * 1.4426950408889634f;  // 1/sqrt(64) * log2(e)
    const long SL = 1048576L;  // one batch slice: 2048 x 512 elements
    dim3 blk(256, 1, 1);

    hipMemsetAsync(counts, 0, 16, stream);
    hipMemsetAsync(perm, 0xFF, 8448 * 4, stream);

    // ---- self attention (batch-chunked QKV + attn) ----
    for (int b = 0; b < 4; ++b) {
        gemm_f<<<dim3(32, 8), blk, 0, stream>>>(x + b * SL, 512, sa_in_w, 512, 0, 0,
            sa_in_b, 0, P1, 512, 512, 0, nullptr, nullptr, nullptr);
        gemm_f<<<dim3(32, 8), blk, 0, stream>>>(x + b * SL, 512, sa_in_w + 262144, 512, 0, 0,
            sa_in_b + 512, 0, P1 + SL, 512, 512, 0, nullptr, nullptr, nullptr);
        gemm_f<<<dim3(32, 8), blk, 0, stream>>>(x + b * SL, 512, sa_in_w + 524288, 512, 0, 0,
            sa_in_b + 1024, 0, P1 + 2 * SL, 512, 512, 0, nullptr, nullptr, nullptr);
        attn_f<<<dim3(32, 8, 1), blk, 0, stream>>>(P1, P1 + SL, P1 + 2 * SL, P0 + b * SL, 2048, sc);
    }
    gemm_f<<<dim3(128, 8), blk, 0, stream>>>(P0, 512, sa_out_w, 512, 0, 0,
        sa_out_b, 0, P1, 512, 512, 0, nullptr, nullptr, nullptr);
    ln_f<<<dim3(2048), blk, 0, stream>>>(x, P1, ln1_g, ln1_b, P2);  // x1 -> P2

    // ---- cross attention (batch-chunked) ----
    for (int b = 0; b < 4; ++b) {
        gemm_f<<<dim3(32, 8), blk, 0, stream>>>(P2 + b * SL, 512, ca_in_w, 512, 0, 0,
            ca_in_b, 0, P1, 512, 512, 0, nullptr, nullptr, nullptr);
        gemm_f<<<dim3(32, 8), blk, 0, stream>>>(mem + b * SL, 512, ca_in_w + 262144, 512, 0, 0,
            ca_in_b + 512, 0, P1 + SL, 512, 512, 0, nullptr, nullptr, nullptr);
        gemm_f<<<dim3(32, 8), blk, 0, stream>>>(mem + b * SL, 512, ca_in_w + 524288, 512, 0, 0,
            ca_in_b + 1024, 0, P1 + 2 * SL, 512, 512, 0, nullptr, nullptr, nullptr);
        attn_f<<<dim3(32, 8, 1), blk, 0, stream>>>(P1, P1 + SL, P1 + 2 * SL, P0 + b * SL, 2048, sc);
    }
    gemm_f<<<dim3(128, 8), blk, 0, stream>>>(P0, 512, ca_out_w, 512, 0, 0,
        ca_out_b, 0, P1, 512, 512, 0, nullptr, nullptr, nullptr);
    ln_f<<<dim3(2048), blk, 0, stream>>>(P2, P1, ln2_g, ln2_b, P0);  // x2 -> P0

    // ---- MoE (top-1, grouped, H chunked through P1; ymoe -> P2) ----
    route_f<<<dim3(2048), blk, 0, stream>>>(P0, gate_w, gate_b, idx, counts);
    plan_k<<<dim3(1), dim3(64), 0, stream>>>(counts, cursors, tile_e);
    scatter_k<<<dim3(32), blk, 0, stream>>>(idx, cursors, perm);
    for (int c = 0; c < 5; ++c) {
        const int t0 = c * 32;
        const int ntc = (132 - t0) < 32 ? (132 - t0) : 32;
        gemm_f<<<dim3(ntc, 32), blk, 0, stream>>>(P0, 512, w1, 2048, 1048576L, 1,
            b1, 2048, P1, 2048, 512, 1, perm + t0 * 64, nullptr, tile_e + t0);
        gemm_f<<<dim3(ntc, 8), blk, 0, stream>>>(P1, 2048, w2, 512, 1048576L, 1,
            b2, 512, P2, 512, 2048, 0, nullptr, perm + t0 * 64, tile_e + t0);
    }
    ln_f<<<dim3(2048), blk, 0, stream>>>(P0, P2, ln3_g, ln3_b, (float*)d_out);
}

// Round 5
// 1219.982 us; speedup vs baseline: 2.1506x; 2.1506x over previous
//
#include <hip/hip_runtime.h>

typedef unsigned short u16;
typedef __attribute__((ext_vector_type(8))) short s16x8;
typedef __attribute__((ext_vector_type(8))) unsigned short u16x8;
typedef __attribute__((ext_vector_type(4))) unsigned short u16x4;
typedef __attribute__((ext_vector_type(4))) float f32x4;

#define DEV static __device__ __forceinline__
#define MFMA __builtin_amdgcn_mfma_f32_16x16x32_bf16

DEV float bf2f(u16 u) { return __uint_as_float(((unsigned)u) << 16); }
DEV u16 f2bf(float f) {
    unsigned u = __float_as_uint(f);
    return (u16)((u + 0x7FFFu + ((u >> 16) & 1u)) >> 16);
}
DEV void split2(float v, u16& hi, u16& lo) {
    hi = f2bf(v);
    lo = f2bf(v - bf2f(hi));
}

// ===========================================================================
// FAST-PATH KERNELS (bf16 hi/lo plane pipeline)
// ===========================================================================

// Split fp32 -> bf16 hi/lo planes, elementwise. n multiple of 2048.
__global__ __launch_bounds__(256) void split_k(
    const float* __restrict__ src, u16* __restrict__ dh, u16* __restrict__ dl, long n)
{
    const long i = ((long)blockIdx.x * 256 + threadIdx.x) * 8;
    if (i >= n) return;
    float4 f0 = *(const float4*)(src + i);
    float4 f1 = *(const float4*)(src + i + 4);
    float v[8] = {f0.x, f0.y, f0.z, f0.w, f1.x, f1.y, f1.z, f1.w};
    u16x8 h8, l8;
    for (int j = 0; j < 8; ++j) { u16 hh, ll; split2(v[j], hh, ll); h8[j] = hh; l8[j] = ll; }
    *(u16x8*)(dh + i) = h8;
    *(u16x8*)(dl + i) = l8;
}

// Transpose+split (hi only): src [E][K][N] fp32 -> dst [E][N][K] bf16.
__global__ __launch_bounds__(256) void splitT_k(
    const float* __restrict__ src, u16* __restrict__ dst, int K, int N)
{
    __shared__ u16 tile[64 * 72];
    const int e = blockIdx.z;
    const int n0 = blockIdx.x * 64, k0 = blockIdx.y * 64;
    const long estride = (long)K * N;
    const int tid = threadIdx.x;
    const int tr = tid >> 2, tc = (tid & 3) * 16;
    {
        const float* sp = src + e * estride + (long)(k0 + tr) * N + n0 + tc;
        for (int j = 0; j < 16; j += 4) {
            float4 f = *(const float4*)(sp + j);
            tile[tr * 72 + tc + j + 0] = f2bf(f.x);
            tile[tr * 72 + tc + j + 1] = f2bf(f.y);
            tile[tr * 72 + tc + j + 2] = f2bf(f.z);
            tile[tr * 72 + tc + j + 3] = f2bf(f.w);
        }
    }
    __syncthreads();
    {
        const int tn = tid >> 2, tk = (tid & 3) * 16;
        u16* dp = dst + e * estride + (long)(n0 + tn) * K + k0 + tk;
        u16x8 o0, o1;
        for (int j = 0; j < 8; ++j) {
            o0[j] = tile[(tk + j) * 72 + tn];
            o1[j] = tile[(tk + 8 + j) * 72 + tn];
        }
        *(u16x8*)(dp) = o0;
        *(u16x8*)(dp + 8) = o1;
    }
}

// ---------------------------------------------------------------------------
// GEMM (plane pipeline): C = act(A @ B^T + bias).
// A: fp32 (Af, split in staging) or bf16 planes (Ahp / Alp). a_lo: use lo term.
// B: bf16 planes (Bh required, Bl optional). 3-term split MFMA when both lo.
// Out: fp32 (Cf, optional perm_out scatter) and/or bf16 planes (Ch [+lo at
// clo_off]); plane cols >=512 routed to tensor t=col>>ts at t*tstride.
// ---------------------------------------------------------------------------
__global__ __launch_bounds__(256) void gemm_s(
    const float* __restrict__ Af, const u16* __restrict__ Ahp, const u16* __restrict__ Alp,
    int lda, int a_lo, const int* __restrict__ perm_in,
    const u16* __restrict__ Bh, const u16* __restrict__ Bl, int ldb, long b_estride,
    const int* __restrict__ tile_expert,
    const float* __restrict__ bias, int bias_estride,
    float* __restrict__ Cf, int ldcf, const int* __restrict__ perm_out,
    u16* __restrict__ Ch, long clo_off, int ldcp, int ts, long tstride,
    int K, int act)
{
    __shared__ u16 As[64 * 40], Als[64 * 40];
    __shared__ u16 Bs[64 * 40], Bls[64 * 40];
    const int mt = blockIdx.x, nt = blockIdx.y;
    int e = 0;
    if (tile_expert) { e = tile_expert[mt]; if (e < 0) return; }
    const int tid = threadIdx.x, lane = tid & 63, w = tid >> 6;
    const int wr = (w >> 1) * 32, wc = (w & 1) * 32;
    const int quad = lane >> 4, l15 = lane & 15;
    const int b_lo = (Bl != nullptr);

    const u16* Bhb = Bh + (long)e * b_estride;
    const u16* Blb = b_lo ? (Bl + (long)e * b_estride) : nullptr;

    const int r2 = tid >> 3, c4 = (tid & 7) * 4;   // fp32-A staging
    const int r1 = tid >> 2, c8 = (tid & 3) * 8;   // plane staging
    long arow0 = 0, arow1 = 0, arowb = 0;
    bool v0 = true, v1 = true, vb = true;
    if (perm_in) {
        if (Af) {
            int p0 = perm_in[mt * 64 + r2];      v0 = p0 >= 0; arow0 = p0 < 0 ? 0 : p0;
            int p1 = perm_in[mt * 64 + r2 + 32]; v1 = p1 >= 0; arow1 = p1 < 0 ? 0 : p1;
        } else {
            int pb = perm_in[mt * 64 + r1];      vb = pb >= 0; arowb = pb < 0 ? 0 : pb;
        }
    } else {
        arow0 = (long)mt * 64 + r2; arow1 = arow0 + 32; arowb = (long)mt * 64 + r1;
    }

    f32x4 acc[2][2] = {};

    for (int k0 = 0; k0 < K; k0 += 32) {
        __syncthreads();
        if (Af) {
            for (int half = 0; half < 2; ++half) {
                const int row = half * 32 + r2;
                const long ar = half ? arow1 : arow0;
                const bool va = half ? v1 : v0;
                float4 v = va ? *(const float4*)(Af + ar * (long)lda + k0 + c4)
                              : make_float4(0.f, 0.f, 0.f, 0.f);
                float vv[4] = {v.x, v.y, v.z, v.w};
                u16x4 h4, l4;
                for (int i = 0; i < 4; ++i) { u16 hh, ll; split2(vv[i], hh, ll); h4[i] = hh; l4[i] = ll; }
                *(u16x4*)&As[row * 40 + c4] = h4;
                if (a_lo) *(u16x4*)&Als[row * 40 + c4] = l4;
            }
        } else {
            const long ao = arowb * (long)lda + k0 + c8;
            u16x8 h8 = vb ? *(const u16x8*)(Ahp + ao) : (u16x8)(u16)0;
            *(u16x8*)&As[r1 * 40 + c8] = h8;
            if (a_lo) {
                u16x8 l8 = vb ? *(const u16x8*)(Alp + ao) : (u16x8)(u16)0;
                *(u16x8*)&Als[r1 * 40 + c8] = l8;
            }
        }
        {
            const long bo = ((long)nt * 64 + r1) * ldb + k0 + c8;
            *(u16x8*)&Bs[r1 * 40 + c8] = *(const u16x8*)(Bhb + bo);
            if (b_lo) *(u16x8*)&Bls[r1 * 40 + c8] = *(const u16x8*)(Blb + bo);
        }
        __syncthreads();
        s16x8 ah0 = *(const s16x8*)&As[(wr + l15) * 40 + quad * 8];
        s16x8 ah1 = *(const s16x8*)&As[(wr + 16 + l15) * 40 + quad * 8];
        s16x8 bh0 = *(const s16x8*)&Bs[(wc + l15) * 40 + quad * 8];
        s16x8 bh1 = *(const s16x8*)&Bs[(wc + 16 + l15) * 40 + quad * 8];
        acc[0][0] = MFMA(ah0, bh0, acc[0][0], 0, 0, 0);
        acc[0][1] = MFMA(ah0, bh1, acc[0][1], 0, 0, 0);
        acc[1][0] = MFMA(ah1, bh0, acc[1][0], 0, 0, 0);
        acc[1][1] = MFMA(ah1, bh1, acc[1][1], 0, 0, 0);
        if (a_lo) {
            s16x8 al0 = *(const s16x8*)&Als[(wr + l15) * 40 + quad * 8];
            s16x8 al1 = *(const s16x8*)&Als[(wr + 16 + l15) * 40 + quad * 8];
            acc[0][0] = MFMA(al0, bh0, acc[0][0], 0, 0, 0);
            acc[0][1] = MFMA(al0, bh1, acc[0][1], 0, 0, 0);
            acc[1][0] = MFMA(al1, bh0, acc[1][0], 0, 0, 0);
            acc[1][1] = MFMA(al1, bh1, acc[1][1], 0, 0, 0);
        }
        if (b_lo) {
            s16x8 bl0 = *(const s16x8*)&Bls[(wc + l15) * 40 + quad * 8];
            s16x8 bl1 = *(const s16x8*)&Bls[(wc + 16 + l15) * 40 + quad * 8];
            acc[0][0] = MFMA(ah0, bl0, acc[0][0], 0, 0, 0);
            acc[0][1] = MFMA(ah0, bl1, acc[0][1], 0, 0, 0);
            acc[1][0] = MFMA(ah1, bl0, acc[1][0], 0, 0, 0);
            acc[1][1] = MFMA(ah1, bl1, acc[1][1], 0, 0, 0);
        }
    }

    const float* bp = bias + (long)e * bias_estride;
    for (int mi = 0; mi < 2; ++mi) {
        for (int r = 0; r < 4; ++r) {
            const int rloc = wr + mi * 16 + quad * 4 + r;  // C/D: row=(lane>>4)*4+reg
            const long lrow = (long)mt * 64 + rloc;
            for (int ni = 0; ni < 2; ++ni) {
                const int colg = nt * 64 + wc + ni * 16 + l15;  // C/D: col=lane&15
                float v = acc[mi][ni][r] + bp[colg];
                if (act == 1) v = 0.5f * v * (1.f + erff(v * 0.7071067811865475f));
                if (Cf) {
                    long orow = lrow;
                    if (perm_out) { int po = perm_out[mt * 64 + rloc]; if (po < 0) continue; orow = po; }
                    Cf[orow * (long)ldcf + colg] = v;
                }
                if (Ch) {
                    const int t = colg >> ts;
                    const int cc = colg - (t << ts);
                    const long po = (long)t * tstride + lrow * (long)ldcp + cc;
                    u16 hh, ll; split2(v, hh, ll);
                    Ch[po] = hh;
                    if (clo_off) Ch[po + clo_off] = ll;
                }
            }
        }
    }
}

// ---------------------------------------------------------------------------
// Flash attention on pre-split hi/lo planes. Q/K/V tensors hold Z*2048 rows
// (lo plane at +plo). Block = 64 Q rows of one (z,h); wave = 16 rows;
// 32-key tiles; split-3 MFMA; online softmax in scaled-log2 units.
// O written as planes (lo at +olo) at rows orow_base + z*2048 + ...
// ---------------------------------------------------------------------------
__global__ __launch_bounds__(256) void attn_p(
    const u16* __restrict__ Qh, const u16* __restrict__ Kh, const u16* __restrict__ Vh,
    long plo, u16* __restrict__ Oh, long olo, int orow_base, float sc)
{
    __shared__ u16 Khs[32 * 72], Kls[32 * 72];
    __shared__ u16 Vhs[64 * 40], Vls[64 * 40];
    __shared__ float Ss[4 * 16 * 36];
    const int z = blockIdx.z, h = blockIdx.y, qt = blockIdx.x;
    const int tid = threadIdx.x, lane = tid & 63, w = tid >> 6;
    const int quad = lane >> 4, l15 = lane & 15;

    const long qoff = ((long)z * 2048 + qt * 64 + w * 16 + l15) * 512 + h * 64 + quad * 8;
    s16x8 qh0 = *(const s16x8*)(Qh + qoff);
    s16x8 qh1 = *(const s16x8*)(Qh + qoff + 32);
    s16x8 ql0 = *(const s16x8*)(Qh + plo + qoff);
    s16x8 ql1 = *(const s16x8*)(Qh + plo + qoff + 32);

    const int kr = tid >> 3, kc = (tid & 7) * 8;       // K stage: 32 keys x 64 dims
    const int vkey = tid & 31, vhd0 = (tid >> 5) * 8;  // V stage: transpose

    float m_run = -1e30f, l_run = 0.f;
    f32x4 oacc[4] = {};
    float* Sw = &Ss[w * 16 * 36];

    for (int t = 0; t < 64; ++t) {
        __syncthreads();
        {
            const long ko = ((long)z * 2048 + t * 32 + kr) * 512 + h * 64 + kc;
            *(u16x8*)&Khs[kr * 72 + kc] = *(const u16x8*)(Kh + ko);
            *(u16x8*)&Kls[kr * 72 + kc] = *(const u16x8*)(Kh + plo + ko);
        }
        {
            const long vo = ((long)z * 2048 + t * 32 + vkey) * 512 + h * 64 + vhd0;
            u16x8 vh8 = *(const u16x8*)(Vh + vo);
            u16x8 vl8 = *(const u16x8*)(Vh + plo + vo);
            for (int i = 0; i < 8; ++i) {
                Vhs[(vhd0 + i) * 40 + vkey] = vh8[i];
                Vls[(vhd0 + i) * 40 + vkey] = vl8[i];
            }
        }
        __syncthreads();
        f32x4 s0 = {0.f, 0.f, 0.f, 0.f}, s1 = {0.f, 0.f, 0.f, 0.f};
        {
            s16x8 kh00 = *(const s16x8*)&Khs[l15 * 72 + quad * 8];
            s16x8 kl00 = *(const s16x8*)&Kls[l15 * 72 + quad * 8];
            s16x8 kh01 = *(const s16x8*)&Khs[l15 * 72 + 32 + quad * 8];
            s16x8 kl01 = *(const s16x8*)&Kls[l15 * 72 + 32 + quad * 8];
            s0 = MFMA(qh0, kh00, s0, 0, 0, 0);
            s0 = MFMA(ql0, kh00, s0, 0, 0, 0);
            s0 = MFMA(qh0, kl00, s0, 0, 0, 0);
            s0 = MFMA(qh1, kh01, s0, 0, 0, 0);
            s0 = MFMA(ql1, kh01, s0, 0, 0, 0);
            s0 = MFMA(qh1, kl01, s0, 0, 0, 0);
            s16x8 kh10 = *(const s16x8*)&Khs[(16 + l15) * 72 + quad * 8];
            s16x8 kl10 = *(const s16x8*)&Kls[(16 + l15) * 72 + quad * 8];
            s16x8 kh11 = *(const s16x8*)&Khs[(16 + l15) * 72 + 32 + quad * 8];
            s16x8 kl11 = *(const s16x8*)&Kls[(16 + l15) * 72 + 32 + quad * 8];
            s1 = MFMA(qh0, kh10, s1, 0, 0, 0);
            s1 = MFMA(ql0, kh10, s1, 0, 0, 0);
            s1 = MFMA(qh0, kl10, s1, 0, 0, 0);
            s1 = MFMA(qh1, kh11, s1, 0, 0, 0);
            s1 = MFMA(ql1, kh11, s1, 0, 0, 0);
            s1 = MFMA(qh1, kl11, s1, 0, 0, 0);
        }
        for (int r = 0; r < 4; ++r) {
            Sw[(quad * 4 + r) * 36 + l15]      = s0[r];
            Sw[(quad * 4 + r) * 36 + 16 + l15] = s1[r];
        }
        __syncthreads();
        float p[8]; float lm = -1e30f;
        const float* srow = &Sw[l15 * 36 + quad * 8];
        for (int j = 0; j < 8; ++j) { p[j] = srow[j] * sc; lm = fmaxf(lm, p[j]); }
        lm = fmaxf(lm, __shfl_xor(lm, 16));
        lm = fmaxf(lm, __shfl_xor(lm, 32));
        const float m_new = fmaxf(m_run, lm);
        const float alpha = exp2f(m_run - m_new);
        float ts = 0.f;
        for (int j = 0; j < 8; ++j) { p[j] = exp2f(p[j] - m_new); ts += p[j]; }
        ts += __shfl_xor(ts, 16);
        ts += __shfl_xor(ts, 32);
        l_run = l_run * alpha + ts;
        m_run = m_new;
        s16x8 ph, pl;
        for (int j = 0; j < 8; ++j) {
            u16 hh, ll; split2(p[j], hh, ll);
            ph[j] = (short)hh; pl[j] = (short)ll;
        }
        float ar[4];
        for (int r = 0; r < 4; ++r) ar[r] = __shfl(alpha, quad * 4 + r);
        for (int tt = 0; tt < 4; ++tt) {
            f32x4 oa = oacc[tt];
            oa[0] *= ar[0]; oa[1] *= ar[1]; oa[2] *= ar[2]; oa[3] *= ar[3];
            s16x8 vh = *(const s16x8*)&Vhs[(tt * 16 + l15) * 40 + quad * 8];
            s16x8 vl = *(const s16x8*)&Vls[(tt * 16 + l15) * 40 + quad * 8];
            oa = MFMA(ph, vh, oa, 0, 0, 0);
            oa = MFMA(pl, vh, oa, 0, 0, 0);
            oa = MFMA(ph, vl, oa, 0, 0, 0);
            oacc[tt] = oa;
        }
    }
    float linv[4];
    for (int r = 0; r < 4; ++r) linv[r] = 1.f / fmaxf(__shfl(l_run, quad * 4 + r), 1e-35f);
    const long obase = ((long)orow_base + z * 2048 + qt * 64 + w * 16 + quad * 4) * 512 + h * 64;
    for (int tt = 0; tt < 4; ++tt)
        for (int r = 0; r < 4; ++r) {
            u16 hh, ll; split2(oacc[tt][r] * linv[r], hh, ll);
            const long oo = obase + (long)r * 512 + tt * 16 + l15;
            Oh[oo] = hh;
            Oh[olo + oo] = ll;
        }
}

// ---------------------------------------------------------------------------
// Residual + LayerNorm (D=512). a/b each either fp32 or hi/lo planes.
// Output fp32 and/or planes.
// ---------------------------------------------------------------------------
__global__ __launch_bounds__(256) void ln_p(
    const float* __restrict__ af, const u16* __restrict__ ah, long alo,
    const float* __restrict__ bf, const u16* __restrict__ bh, long blo,
    const float* __restrict__ g, const float* __restrict__ be,
    float* __restrict__ of, u16* __restrict__ oh, long olo)
{
    const int tid = threadIdx.x, lane = tid & 63, w = tid >> 6;
    const long base = ((long)blockIdx.x * 4 + w) * 512 + lane * 8;
    float v[8];
    if (af) {
        float4 f0 = *(const float4*)(af + base);
        float4 f1 = *(const float4*)(af + base + 4);
        v[0] = f0.x; v[1] = f0.y; v[2] = f0.z; v[3] = f0.w;
        v[4] = f1.x; v[5] = f1.y; v[6] = f1.z; v[7] = f1.w;
    } else {
        u16x8 hh = *(const u16x8*)(ah + base);
        u16x8 ll = *(const u16x8*)(ah + alo + base);
        for (int j = 0; j < 8; ++j) v[j] = bf2f(hh[j]) + bf2f(ll[j]);
    }
    if (bf) {
        float4 f0 = *(const float4*)(bf + base);
        float4 f1 = *(const float4*)(bf + base + 4);
        v[0] += f0.x; v[1] += f0.y; v[2] += f0.z; v[3] += f0.w;
        v[4] += f1.x; v[5] += f1.y; v[6] += f1.z; v[7] += f1.w;
    } else {
        u16x8 hh = *(const u16x8*)(bh + base);
        u16x8 ll = *(const u16x8*)(bh + blo + base);
        for (int j = 0; j < 8; ++j) v[j] += bf2f(hh[j]) + bf2f(ll[j]);
    }
    float s = 0.f, sq = 0.f;
    for (int j = 0; j < 8; ++j) { s += v[j]; sq += v[j] * v[j]; }
    for (int m = 1; m < 64; m <<= 1) { s += __shfl_xor(s, m); sq += __shfl_xor(sq, m); }
    const float mu = s * (1.f / 512.f);
    const float var = fmaxf(sq * (1.f / 512.f) - mu * mu, 0.f);
    const float rs = rsqrtf(var + 1e-5f);
    float4 ga = *(const float4*)(g + lane * 8);
    float4 gb = *(const float4*)(g + lane * 8 + 4);
    float4 ba = *(const float4*)(be + lane * 8);
    float4 bb = *(const float4*)(be + lane * 8 + 4);
    float gg[8] = {ga.x, ga.y, ga.z, ga.w, gb.x, gb.y, gb.z, gb.w};
    float bv[8] = {ba.x, ba.y, ba.z, ba.w, bb.x, bb.y, bb.z, bb.w};
    float o[8];
    for (int j = 0; j < 8; ++j) o[j] = (v[j] - mu) * rs * gg[j] + bv[j];
    if (of) {
        *(float4*)(of + base)     = make_float4(o[0], o[1], o[2], o[3]);
        *(float4*)(of + base + 4) = make_float4(o[4], o[5], o[6], o[7]);
    }
    if (oh) {
        u16x8 h8, l8;
        for (int j = 0; j < 8; ++j) { u16 hh, ll; split2(o[j], hh, ll); h8[j] = hh; l8[j] = ll; }
        *(u16x8*)(oh + base) = h8;
        *(u16x8*)(oh + olo + base) = l8;
    }
}

// Routing from hi/lo planes (argmax of logits). One wave per token.
__global__ __launch_bounds__(256) void route_p(
    const u16* __restrict__ xh, long xlo,
    const float* __restrict__ gw, const float* __restrict__ gb,
    int* __restrict__ idx, int* __restrict__ counts)
{
    const int tid = threadIdx.x, lane = tid & 63, w = tid >> 6;
    const long row = (long)blockIdx.x * 4 + w;
    const long base = row * 512 + lane * 8;
    u16x8 hh = *(const u16x8*)(xh + base);
    u16x8 ll = *(const u16x8*)(xh + xlo + base);
    float xf[8];
    for (int j = 0; j < 8; ++j) xf[j] = bf2f(hh[j]) + bf2f(ll[j]);
    float best = -1e30f; int bi = 0;
    for (int e = 0; e < 4; ++e) {
        float4 w0 = *(const float4*)(gw + e * 512 + lane * 8);
        float4 w1 = *(const float4*)(gw + e * 512 + lane * 8 + 4);
        float wf[8] = {w0.x, w0.y, w0.z, w0.w, w1.x, w1.y, w1.z, w1.w};
        float d = 0.f;
        for (int j = 0; j < 8; ++j) d += xf[j] * wf[j];
        for (int m = 1; m < 64; m <<= 1) d += __shfl_xor(d, m);
        d += gb[e];
        if (d > best) { best = d; bi = e; }
    }
    if (lane == 0) { idx[row] = bi; atomicAdd(&counts[bi], 1); }
}

__global__ void plan_k(const int* __restrict__ counts, int* __restrict__ cursors,
                       int* __restrict__ tile_expert)
{
    if (threadIdx.x != 0 || blockIdx.x != 0) return;
    int off = 0;
    for (int e = 0; e < 4; ++e) {
        cursors[e] = off;
        int nt = (counts[e] + 63) >> 6;
        int t0 = off >> 6;
        for (int i = 0; i < nt; ++i) tile_expert[t0 + i] = e;
        off += nt << 6;
    }
    for (int t = off >> 6; t < 132; ++t) tile_expert[t] = -1;
}

__global__ __launch_bounds__(256) void scatter_k(
    const int* __restrict__ idx, int* __restrict__ cursors, int* __restrict__ perm)
{
    const int t = blockIdx.x * 256 + threadIdx.x;
    const int e = idx[t];
    const int pos = atomicAdd(&cursors[e], 1);
    perm[pos] = t;
}

// ===========================================================================
// FALLBACK KERNELS (proven R4 path, used when ws_size is too small)
// ===========================================================================
__global__ __launch_bounds__(256) void gemm_f(
    const float* __restrict__ A, int lda,
    const float* __restrict__ Bw, int ldb, long b_estride, int b_kn,
    const float* __restrict__ bias, int bias_estride,
    float* __restrict__ C, int ldc,
    int K, int act,
    const int* __restrict__ perm_in,
    const int* __restrict__ perm_out,
    const int* __restrict__ tile_expert)
{
    __shared__ u16 Ah[64 * 40], Al[64 * 40];
    __shared__ u16 Bh[64 * 40], Bl[64 * 40];
    const int mt = blockIdx.x, nt = blockIdx.y;
    int e = 0;
    if (tile_expert) { e = tile_expert[mt]; if (e < 0) return; }
    const int tid = threadIdx.x, lane = tid & 63, w = tid >> 6;
    const int wr = (w >> 1) * 32, wc = (w & 1) * 32;
    const int quad = lane >> 4, l15 = lane & 15;
    const float* Bbase = Bw + (long)e * b_estride;
    const int r1 = tid >> 2, c8 = (tid & 3) * 8;
    long arow; bool avalid = true;
    if (perm_in) { int p = perm_in[mt * 64 + r1]; avalid = p >= 0; arow = p < 0 ? 0 : p; }
    else arow = (long)mt * 64 + r1;
    const float* Ap = A + arow * (long)lda + c8;
    f32x4 acc[2][2] = {};
    for (int k0 = 0; k0 < K; k0 += 32) {
        __syncthreads();
        {
            float va[8] = {};
            if (avalid) {
                float4 f0 = *(const float4*)(Ap + k0);
                float4 f1 = *(const float4*)(Ap + k0 + 4);
                va[0] = f0.x; va[1] = f0.y; va[2] = f0.z; va[3] = f0.w;
                va[4] = f1.x; va[5] = f1.y; va[6] = f1.z; va[7] = f1.w;
            }
            u16x8 h8, l8;
            for (int i = 0; i < 8; ++i) { u16 hh, ll; split2(va[i], hh, ll); h8[i] = hh; l8[i] = ll; }
            *(u16x8*)&Ah[r1 * 40 + c8] = h8;
            *(u16x8*)&Al[r1 * 40 + c8] = l8;
        }
        if (b_kn) {
            const int kr = tid >> 3, nc = (tid & 7) * 8;
            const float* bp = Bbase + (long)(k0 + kr) * ldb + nt * 64 + nc;
            float4 f0 = *(const float4*)(bp);
            float4 f1 = *(const float4*)(bp + 4);
            float vb[8] = {f0.x, f0.y, f0.z, f0.w, f1.x, f1.y, f1.z, f1.w};
            for (int i = 0; i < 8; ++i) {
                u16 hh, ll; split2(vb[i], hh, ll);
                Bh[(nc + i) * 40 + kr] = hh;
                Bl[(nc + i) * 40 + kr] = ll;
            }
        } else {
            const float* bp = Bbase + ((long)nt * 64 + r1) * ldb + k0 + c8;
            float4 f0 = *(const float4*)(bp);
            float4 f1 = *(const float4*)(bp + 4);
            float vb[8] = {f0.x, f0.y, f0.z, f0.w, f1.x, f1.y, f1.z, f1.w};
            u16x8 h8, l8;
            for (int i = 0; i < 8; ++i) { u16 hh, ll; split2(vb[i], hh, ll); h8[i] = hh; l8[i] = ll; }
            *(u16x8*)&Bh[r1 * 40 + c8] = h8;
            *(u16x8*)&Bl[r1 * 40 + c8] = l8;
        }
        __syncthreads();
        s16x8 ah0 = *(const s16x8*)&Ah[(wr + l15) * 40 + quad * 8];
        s16x8 ah1 = *(const s16x8*)&Ah[(wr + 16 + l15) * 40 + quad * 8];
        s16x8 al0 = *(const s16x8*)&Al[(wr + l15) * 40 + quad * 8];
        s16x8 al1 = *(const s16x8*)&Al[(wr + 16 + l15) * 40 + quad * 8];
        s16x8 bh0 = *(const s16x8*)&Bh[(wc + l15) * 40 + quad * 8];
        s16x8 bh1 = *(const s16x8*)&Bh[(wc + 16 + l15) * 40 + quad * 8];
        s16x8 bl0 = *(const s16x8*)&Bl[(wc + l15) * 40 + quad * 8];
        s16x8 bl1 = *(const s16x8*)&Bl[(wc + 16 + l15) * 40 + quad * 8];
        acc[0][0] = MFMA(ah0, bh0, acc[0][0], 0, 0, 0);
        acc[0][0] = MFMA(al0, bh0, acc[0][0], 0, 0, 0);
        acc[0][0] = MFMA(ah0, bl0, acc[0][0], 0, 0, 0);
        acc[0][1] = MFMA(ah0, bh1, acc[0][1], 0, 0, 0);
        acc[0][1] = MFMA(al0, bh1, acc[0][1], 0, 0, 0);
        acc[0][1] = MFMA(ah0, bl1, acc[0][1], 0, 0, 0);
        acc[1][0] = MFMA(ah1, bh0, acc[1][0], 0, 0, 0);
        acc[1][0] = MFMA(al1, bh0, acc[1][0], 0, 0, 0);
        acc[1][0] = MFMA(ah1, bl0, acc[1][0], 0, 0, 0);
        acc[1][1] = MFMA(ah1, bh1, acc[1][1], 0, 0, 0);
        acc[1][1] = MFMA(al1, bh1, acc[1][1], 0, 0, 0);
        acc[1][1] = MFMA(ah1, bl1, acc[1][1], 0, 0, 0);
    }
    const float* bp = bias + (long)e * bias_estride + nt * 64;
    for (int mi = 0; mi < 2; ++mi) {
        for (int r = 0; r < 4; ++r) {
            const int rloc = wr + mi * 16 + quad * 4 + r;
            long orow;
            if (perm_out) { int po = perm_out[mt * 64 + rloc]; if (po < 0) continue; orow = po; }
            else orow = (long)mt * 64 + rloc;
            float* crow = C + orow * (long)ldc + (long)nt * 64;
            for (int ni = 0; ni < 2; ++ni) {
                const int col = wc + ni * 16 + l15;
                float v = acc[mi][ni][r] + bp[col];
                if (act == 1) v = 0.5f * v * (1.f + erff(v * 0.7071067811865475f));
                crow[col] = v;
            }
        }
    }
}

__global__ __launch_bounds__(256) void attn_f(
    const float* __restrict__ Q, const float* __restrict__ K,
    const float* __restrict__ V, float* __restrict__ O,
    int LK, float sc)
{
    __shared__ u16 Khs[32 * 72], Kls[32 * 72];
    __shared__ u16 Vhs[64 * 40], Vls[64 * 40];
    __shared__ float Ss[4 * 16 * 36];
    const int h = blockIdx.y, qt = blockIdx.x;
    const int tid = threadIdx.x, lane = tid & 63, w = tid >> 6;
    const int quad = lane >> 4, l15 = lane & 15;
    const float* qrow = Q + ((long)qt * 64 + w * 16 + l15) * 512 + h * 64;
    s16x8 qh0, ql0, qh1, ql1;
    {
        float4 f0 = *(const float4*)(qrow + quad * 8);
        float4 f1 = *(const float4*)(qrow + quad * 8 + 4);
        float4 f2 = *(const float4*)(qrow + 32 + quad * 8);
        float4 f3 = *(const float4*)(qrow + 32 + quad * 8 + 4);
        float a[8] = {f0.x, f0.y, f0.z, f0.w, f1.x, f1.y, f1.z, f1.w};
        float c[8] = {f2.x, f2.y, f2.z, f2.w, f3.x, f3.y, f3.z, f3.w};
        for (int i = 0; i < 8; ++i) {
            u16 hh, ll;
            split2(a[i], hh, ll); qh0[i] = (short)hh; ql0[i] = (short)ll;
            split2(c[i], hh, ll); qh1[i] = (short)hh; ql1[i] = (short)ll;
        }
    }
    const int kr = tid >> 3, kc = (tid & 7) * 8;
    const int vkey = tid & 31, vhd0 = (tid >> 5) * 8;
    float m_run = -1e30f, l_run = 0.f;
    f32x4 oacc[4] = {};
    float* Sw = &Ss[w * 16 * 36];
    const int ntile = LK >> 5;
    for (int t = 0; t < ntile; ++t) {
        __syncthreads();
        {
            const float* kp = K + ((long)t * 32 + kr) * 512 + h * 64 + kc;
            float4 f0 = *(const float4*)(kp);
            float4 f1 = *(const float4*)(kp + 4);
            float a[8] = {f0.x, f0.y, f0.z, f0.w, f1.x, f1.y, f1.z, f1.w};
            u16x8 h8, l8;
            for (int i = 0; i < 8; ++i) { u16 hh, ll; split2(a[i], hh, ll); h8[i] = hh; l8[i] = ll; }
            *(u16x8*)&Khs[kr * 72 + kc] = h8;
            *(u16x8*)&Kls[kr * 72 + kc] = l8;
        }
        {
            const float* vp = V + ((long)t * 32 + vkey) * 512 + h * 64 + vhd0;
            float4 f0 = *(const float4*)(vp);
            float4 f1 = *(const float4*)(vp + 4);
            float a[8] = {f0.x, f0.y, f0.z, f0.w, f1.x, f1.y, f1.z, f1.w};
            for (int i = 0; i < 8; ++i) {
                u16 hh, ll; split2(a[i], hh, ll);
                Vhs[(vhd0 + i) * 40 + vkey] = hh;
                Vls[(vhd0 + i) * 40 + vkey] = ll;
            }
        }
        __syncthreads();
        f32x4 s0 = {0.f, 0.f, 0.f, 0.f}, s1 = {0.f, 0.f, 0.f, 0.f};
        {
            s16x8 kh00 = *(const s16x8*)&Khs[l15 * 72 + quad * 8];
            s16x8 kl00 = *(const s16x8*)&Kls[l15 * 72 + quad * 8];
            s16x8 kh01 = *(const s16x8*)&Khs[l15 * 72 + 32 + quad * 8];
            s16x8 kl01 = *(const s16x8*)&Kls[l15 * 72 + 32 + quad * 8];
            s0 = MFMA(qh0, kh00, s0, 0, 0, 0);
            s0 = MFMA(ql0, kh00, s0, 0, 0, 0);
            s0 = MFMA(qh0, kl00, s0, 0, 0, 0);
            s0 = MFMA(qh1, kh01, s0, 0, 0, 0);
            s0 = MFMA(ql1, kh01, s0, 0, 0, 0);
            s0 = MFMA(qh1, kl01, s0, 0, 0, 0);
            s16x8 kh10 = *(const s16x8*)&Khs[(16 + l15) * 72 + quad * 8];
            s16x8 kl10 = *(const s16x8*)&Kls[(16 + l15) * 72 + quad * 8];
            s16x8 kh11 = *(const s16x8*)&Khs[(16 + l15) * 72 + 32 + quad * 8];
            s16x8 kl11 = *(const s16x8*)&Kls[(16 + l15) * 72 + 32 + quad * 8];
            s1 = MFMA(qh0, kh10, s1, 0, 0, 0);
            s1 = MFMA(ql0, kh10, s1, 0, 0, 0);
            s1 = MFMA(qh0, kl10, s1, 0, 0, 0);
            s1 = MFMA(qh1, kh11, s1, 0, 0, 0);
            s1 = MFMA(ql1, kh11, s1, 0, 0, 0);
            s1 = MFMA(qh1, kl11, s1, 0, 0, 0);
        }
        for (int r = 0; r < 4; ++r) {
            Sw[(quad * 4 + r) * 36 + l15]      = s0[r];
            Sw[(quad * 4 + r) * 36 + 16 + l15] = s1[r];
        }
        __syncthreads();
        float p[8]; float lm = -1e30f;
        const float* srow = &Sw[l15 * 36 + quad * 8];
        for (int j = 0; j < 8; ++j) { p[j] = srow[j] * sc; lm = fmaxf(lm, p[j]); }
        lm = fmaxf(lm, __shfl_xor(lm, 16));
        lm = fmaxf(lm, __shfl_xor(lm, 32));
        const float m_new = fmaxf(m_run, lm);
        const float alpha = exp2f(m_run - m_new);
        float ts = 0.f;
        for (int j = 0; j < 8; ++j) { p[j] = exp2f(p[j] - m_new); ts += p[j]; }
        ts += __shfl_xor(ts, 16);
        ts += __shfl_xor(ts, 32);
        l_run = l_run * alpha + ts;
        m_run = m_new;
        s16x8 ph, pl;
        for (int j = 0; j < 8; ++j) {
            u16 hh, ll; split2(p[j], hh, ll);
            ph[j] = (short)hh; pl[j] = (short)ll;
        }
        float ar[4];
        for (int r = 0; r < 4; ++r) ar[r] = __shfl(alpha, quad * 4 + r);
        for (int tt = 0; tt < 4; ++tt) {
            f32x4 oa = oacc[tt];
            oa[0] *= ar[0]; oa[1] *= ar[1]; oa[2] *= ar[2]; oa[3] *= ar[3];
            s16x8 vh = *(const s16x8*)&Vhs[(tt * 16 + l15) * 40 + quad * 8];
            s16x8 vl = *(const s16x8*)&Vls[(tt * 16 + l15) * 40 + quad * 8];
            oa = MFMA(ph, vh, oa, 0, 0, 0);
            oa = MFMA(pl, vh, oa, 0, 0, 0);
            oa = MFMA(ph, vl, oa, 0, 0, 0);
            oacc[tt] = oa;
        }
    }
    float linv[4];
    for (int r = 0; r < 4; ++r) linv[r] = 1.f / fmaxf(__shfl(l_run, quad * 4 + r), 1e-35f);
    float* obase = O + ((long)qt * 64 + w * 16 + quad * 4) * 512 + h * 64;
    for (int tt = 0; tt < 4; ++tt)
        for (int r = 0; r < 4; ++r)
            obase[(long)r * 512 + tt * 16 + l15] = oacc[tt][r] * linv[r];
}

// ===========================================================================
extern "C" void kernel_launch(void* const* d_in, const int* in_sizes, int n_in,
                              void* d_out, int out_size, void* d_ws, size_t ws_size,
                              hipStream_t stream)
{
    (void)in_sizes; (void)n_in; (void)out_size;
    const float* x        = (const float*)d_in[0];
    const float* mem      = (const float*)d_in[1];
    const float* sa_in_w  = (const float*)d_in[2];
    const float* sa_in_b  = (const float*)d_in[3];
    const float* sa_out_w = (const float*)d_in[4];
    const float* sa_out_b = (const float*)d_in[5];
    const float* ca_in_w  = (const float*)d_in[6];
    const float* ca_in_b  = (const float*)d_in[7];
    const float* ca_out_w = (const float*)d_in[8];
    const float* ca_out_b = (const float*)d_in[9];
    const float* gate_w   = (const float*)d_in[10];
    const float* gate_b   = (const float*)d_in[11];
    const float* w1       = (const float*)d_in[12];
    const float* b1       = (const float*)d_in[13];
    const float* w2       = (const float*)d_in[14];
    const float* b2       = (const float*)d_in[15];
    const float* ln1_g    = (const float*)d_in[16];
    const float* ln1_b    = (const float*)d_in[17];
    const float* ln2_g    = (const float*)d_in[18];
    const float* ln2_b    = (const float*)d_in[19];
    const float* ln3_g    = (const float*)d_in[20];
    const float* ln3_b    = (const float*)d_in[21];

    const float sc = 0.125f * 1.4426950408889634f;
    dim3 blk(256, 1, 1);
    char* ws = (char*)d_ws;

    const size_t FAST_NEED = 100730416;  // see layout below

    if (ws_size >= FAST_NEED) {
        // -------- fast plane pipeline --------
        // u16 regions (byte offsets):
        // 0         WA: sa_in planes(3,145,728) | sa_out(1,048,576) | ca_in(3,145,728) | ca_out(1,048,576)
        // 8,388,608 WM: w1h(8,388,608) | w2h(8,388,608)   [hi-only, transposed to [E][N][K]]
        // 25,165,824 QKVp (25,165,824): attn planes / MoE H chunk
        // 50,331,648 Op (16,777,216)
        // 67,108,864 P1p planes / ymoe fp32 (16,777,216)
        // 83,886,080 X1p -> X2p planes (16,777,216)
        // 100,663,296 meta
        u16* WA   = (u16*)(ws);
        u16* w1h  = (u16*)(ws + 8388608L);
        u16* w2h  = (u16*)(ws + 16777216L);
        u16* QKVp = (u16*)(ws + 25165824L);
        u16* Op   = (u16*)(ws + 50331648L);
        u16* P1p  = (u16*)(ws + 67108864L);
        float* ymoe = (float*)(ws + 67108864L);
        u16* X1p  = (u16*)(ws + 83886080L);
        int* idx    = (int*)(ws + 100663296L);
        int* perm   = (int*)(ws + 100663296L + 32768);
        int* counts = (int*)(ws + 100663296L + 32768 + 33792);
        int* cursors= (int*)(ws + 100663296L + 32768 + 33792 + 16);
        int* tile_e = (int*)(ws + 100663296L + 32768 + 33792 + 32);

        // plane offsets (elements)
        const long WAe_sa_in = 0, WAe_sa_out = 1572864, WAe_ca_in = 2097152, WAe_ca_out = 3670016;
        const long L_QKV = 2097152;   // lo offset within a 4096x512 tensor
        const long T_QKV = 4194304;   // tensor stride (hi+lo) for 4096x512
        const long L_8K  = 4194304;   // lo offset for 8192x512 tensors
        const long SL    = 1048576;   // 2048x512 fp32 batch slice (elements)

        hipMemsetAsync(counts, 0, 16, stream);
        hipMemsetAsync(perm, 0xFF, 8448 * 4, stream);

        // pre-split weights
        split_k<<<dim3(384), blk, 0, stream>>>(sa_in_w,  WA + WAe_sa_in,  WA + WAe_sa_in + 786432, 786432);
        split_k<<<dim3(128), blk, 0, stream>>>(sa_out_w, WA + WAe_sa_out, WA + WAe_sa_out + 262144, 262144);
        split_k<<<dim3(384), blk, 0, stream>>>(ca_in_w,  WA + WAe_ca_in,  WA + WAe_ca_in + 786432, 786432);
        split_k<<<dim3(128), blk, 0, stream>>>(ca_out_w, WA + WAe_ca_out, WA + WAe_ca_out + 262144, 262144);
        splitT_k<<<dim3(32, 8, 4), blk, 0, stream>>>(w1, w1h, 512, 2048);   // -> [E][2048][512]
        splitT_k<<<dim3(8, 32, 4), blk, 0, stream>>>(w2, w2h, 2048, 512);   // -> [E][512][2048]

        // ---- self attention (half-batch) ----
        for (int hB = 0; hB < 2; ++hB) {
            gemm_s<<<dim3(64, 24), blk, 0, stream>>>(
                x + hB * 2 * SL, nullptr, nullptr, 512, 1, nullptr,
                WA + WAe_sa_in, WA + WAe_sa_in + 786432, 512, 0, nullptr,
                sa_in_b, 0, nullptr, 0, nullptr,
                QKVp, L_QKV, 512, 9, T_QKV, 512, 0);
            attn_p<<<dim3(32, 8, 2), blk, 0, stream>>>(
                QKVp, QKVp + T_QKV, QKVp + 2 * T_QKV, L_QKV, Op, L_8K, hB * 4096, sc);
        }
        gemm_s<<<dim3(128, 8), blk, 0, stream>>>(
            nullptr, Op, Op + L_8K, 512, 1, nullptr,
            WA + WAe_sa_out, WA + WAe_sa_out + 262144, 512, 0, nullptr,
            sa_out_b, 0, nullptr, 0, nullptr,
            P1p, L_8K, 512, 9, 0, 512, 0);
        ln_p<<<dim3(2048), blk, 0, stream>>>(x, nullptr, 0, nullptr, P1p, L_8K,
                                             ln1_g, ln1_b, nullptr, X1p, L_8K);

        // ---- cross attention (half-batch) ----
        for (int hB = 0; hB < 2; ++hB) {
            gemm_s<<<dim3(64, 8), blk, 0, stream>>>(
                nullptr, X1p + hB * L_QKV, X1p + L_8K + hB * L_QKV, 512, 1, nullptr,
                WA + WAe_ca_in, WA + WAe_ca_in + 786432, 512, 0, nullptr,
                ca_in_b, 0, nullptr, 0, nullptr,
                QKVp, L_QKV, 512, 9, T_QKV, 512, 0);
            gemm_s<<<dim3(64, 16), blk, 0, stream>>>(
                mem + hB * 2 * SL, nullptr, nullptr, 512, 1, nullptr,
                WA + WAe_ca_in + 262144, WA + WAe_ca_in + 786432 + 262144, 512, 0, nullptr,
                ca_in_b + 512, 0, nullptr, 0, nullptr,
                QKVp + T_QKV, L_QKV, 512, 9, T_QKV, 512, 0);
            attn_p<<<dim3(32, 8, 2), blk, 0, stream>>>(
                QKVp, QKVp + T_QKV, QKVp + 2 * T_QKV, L_QKV, Op, L_8K, hB * 4096, sc);
        }
        gemm_s<<<dim3(128, 8), blk, 0, stream>>>(
            nullptr, Op, Op + L_8K, 512, 1, nullptr,
            WA + WAe_ca_out, WA + WAe_ca_out + 262144, 512, 0, nullptr,
            ca_out_b, 0, nullptr, 0, nullptr,
            P1p, L_8K, 512, 9, 0, 512, 0);
        ln_p<<<dim3(2048), blk, 0, stream>>>(nullptr, X1p, L_8K, nullptr, P1p, L_8K,
                                             ln2_g, ln2_b, nullptr, X1p, L_8K);  // X2p in-place

        // ---- MoE (top-1, grouped; H hi-plane chunks through QKVp) ----
        route_p<<<dim3(2048), blk, 0, stream>>>(X1p, L_8K, gate_w, gate_b, idx, counts);
        plan_k<<<dim3(1), dim3(64), 0, stream>>>(counts, cursors, tile_e);
        scatter_k<<<dim3(32), blk, 0, stream>>>(idx, cursors, perm);
        for (int c = 0; c < 2; ++c) {
            const int t0 = c * 66;
            gemm_s<<<dim3(66, 32), blk, 0, stream>>>(
                nullptr, X1p, nullptr, 512, 0, perm + t0 * 64,
                w1h, nullptr, 512, 1048576, tile_e + t0,
                b1, 2048, nullptr, 0, nullptr,
                QKVp, 0, 2048, 31, 0, 512, 1);
            gemm_s<<<dim3(66, 8), blk, 0, stream>>>(
                nullptr, QKVp, nullptr, 2048, 0, nullptr,
                w2h, nullptr, 2048, 1048576, tile_e + t0,
                b2, 512, ymoe, 512, perm + t0 * 64,
                nullptr, 0, 0, 31, 0, 2048, 0);
        }
        ln_p<<<dim3(2048), blk, 0, stream>>>(nullptr, X1p, L_8K, ymoe, nullptr, 0,
                                             ln3_g, ln3_b, (float*)d_out, nullptr, 0);
    } else {
        // -------- fallback: proven R4 plan (<= 48.1 MB) --------
        float* P0 = (float*)(ws);
        float* P1 = (float*)(ws + 16777216L);
        float* P2 = (float*)(ws + 33554432L);
        int* idx    = (int*)(ws + 50331648L);
        int* perm   = (int*)(ws + 50331648L + 32768);
        int* counts = (int*)(ws + 50331648L + 32768 + 33792);
        int* cursors= (int*)(ws + 50331648L + 32768 + 33792 + 16);
        int* tile_e = (int*)(ws + 50331648L + 32768 + 33792 + 32);
        const long SL = 1048576L;

        hipMemsetAsync(counts, 0, 16, stream);
        hipMemsetAsync(perm, 0xFF, 8448 * 4, stream);

        for (int b = 0; b < 4; ++b) {
            gemm_f<<<dim3(32, 8), blk, 0, stream>>>(x + b * SL, 512, sa_in_w, 512, 0, 0,
                sa_in_b, 0, P1, 512, 512, 0, nullptr, nullptr, nullptr);
            gemm_f<<<dim3(32, 8), blk, 0, stream>>>(x + b * SL, 512, sa_in_w + 262144, 512, 0, 0,
                sa_in_b + 512, 0, P1 + SL, 512, 512, 0, nullptr, nullptr, nullptr);
            gemm_f<<<dim3(32, 8), blk, 0, stream>>>(x + b * SL, 512, sa_in_w + 524288, 512, 0, 0,
                sa_in_b + 1024, 0, P1 + 2 * SL, 512, 512, 0, nullptr, nullptr, nullptr);
            attn_f<<<dim3(32, 8, 1), blk, 0, stream>>>(P1, P1 + SL, P1 + 2 * SL, P0 + b * SL, 2048, sc);
        }
        gemm_f<<<dim3(128, 8), blk, 0, stream>>>(P0, 512, sa_out_w, 512, 0, 0,
            sa_out_b, 0, P1, 512, 512, 0, nullptr, nullptr, nullptr);
        {
            // residual+LN via ln_p (fp32/fp32 -> fp32)
            ln_p<<<dim3(2048), blk, 0, stream>>>(x, nullptr, 0, P1, nullptr, 0,
                                                 ln1_g, ln1_b, P2, nullptr, 0);
        }
        for (int b = 0; b < 4; ++b) {
            gemm_f<<<dim3(32, 8), blk, 0, stream>>>(P2 + b * SL, 512, ca_in_w, 512, 0, 0,
                ca_in_b, 0, P1, 512, 512, 0, nullptr, nullptr, nullptr);
            gemm_f<<<dim3(32, 8), blk, 0, stream>>>(mem + b * SL, 512, ca_in_w + 262144, 512, 0, 0,
                ca_in_b + 512, 0, P1 + SL, 512, 512, 0, nullptr, nullptr, nullptr);
            gemm_f<<<dim3(32, 8), blk, 0, stream>>>(mem + b * SL, 512, ca_in_w + 524288, 512, 0, 0,
                ca_in_b + 1024, 0, P1 + 2 * SL, 512, 512, 0, nullptr, nullptr, nullptr);
            attn_f<<<dim3(32, 8, 1), blk, 0, stream>>>(P1, P1 + SL, P1 + 2 * SL, P0 + b * SL, 2048, sc);
        }
        gemm_f<<<dim3(128, 8), blk, 0, stream>>>(P0, 512, ca_out_w, 512, 0, 0,
            ca_out_b, 0, P1, 512, 512, 0, nullptr, nullptr, nullptr);
        ln_p<<<dim3(2048), blk, 0, stream>>>(P2, nullptr, 0, P1, nullptr, 0,
                                             ln2_g, ln2_b, P0, nullptr, 0);
        {
            // route on fp32 x2 (P0) via route_p is planes-only; use a tiny trick:
            // reuse gemm-free fp32 routing from R4 semantics with ln_p outputs.
            // (fp32 routing kernel below)
        }
        // fp32 routing: reuse route_p impossible; inline with a lambda-like kernel:
        // use plan: compute logits with gemm_f into P1 (N=4 padded? simpler: small custom)
        // -- dedicated fp32 route kernel:
        extern __global__ void route_f32(const float*, const float*, const float*, int*, int*);
        route_f32<<<dim3(2048), blk, 0, stream>>>(P0, gate_w, gate_b, idx, counts);
        plan_k<<<dim3(1), dim3(64), 0, stream>>>(counts, cursors, tile_e);
        scatter_k<<<dim3(32), blk, 0, stream>>>(idx, cursors, perm);
        for (int c = 0; c < 5; ++c) {
            const int t0 = c * 32;
            const int ntc = (132 - t0) < 32 ? (132 - t0) : 32;
            gemm_f<<<dim3(ntc, 32), blk, 0, stream>>>(P0, 512, w1, 2048, 1048576L, 1,
                b1, 2048, P1, 2048, 512, 1, perm + t0 * 64, nullptr, tile_e + t0);
            gemm_f<<<dim3(ntc, 8), blk, 0, stream>>>(P1, 2048, w2, 512, 1048576L, 1,
                b2, 512, P2, 512, 2048, 0, nullptr, perm + t0 * 64, tile_e + t0);
        }
        ln_p<<<dim3(2048), blk, 0, stream>>>(P0, nullptr, 0, P2, nullptr, 0,
                                             ln3_g, ln3_b, (float*)d_out, nullptr, 0);
    }
}

// fp32 routing kernel (fallback path)
__global__ __launch_bounds__(256) void route_f32(
    const float* __restrict__ x, const float* __restrict__ gw, const float* __restrict__ gb,
    int* __restrict__ idx, int* __restrict__ counts)
{
    const int tid = threadIdx.x, lane = tid & 63, w = tid >> 6;
    const long row = (long)blockIdx.x * 4 + w;
    const float* xr = x + row * 512 + lane * 8;
    float4 f0 = *(const float4*)(xr);
    float4 f1 = *(const float4*)(xr + 4);
    float xf[8] = {f0.x, f0.y, f0.z, f0.w, f1.x, f1.y, f1.z, f1.w};
    float best = -1e30f; int bi = 0;
    for (int e = 0; e < 4; ++e) {
        float4 w0 = *(const float4*)(gw + e * 512 + lane * 8);
        float4 w1 = *(const float4*)(gw + e * 512 + lane * 8 + 4);
        float wf[8] = {w0.x, w0.y, w0.z, w0.w, w1.x, w1.y, w1.z, w1.w};
        float d = 0.f;
        for (int j = 0; j < 8; ++j) d += xf[j] * wf[j];
        for (int m = 1; m < 64; m <<= 1) d += __shfl_xor(d, m);
        d += gb[e];
        if (d > best) { best = d; bi = e; }
    }
    if (lane == 0) { idx[row] = bi; atomicAdd(&counts[bi], 1); }
}

// Round 6
// 1027.565 us; speedup vs baseline: 2.5533x; 1.1873x over previous
//
#include <hip/hip_runtime.h>

typedef unsigned short u16;
typedef __attribute__((ext_vector_type(8))) short s16x8;
typedef __attribute__((ext_vector_type(8))) unsigned short u16x8;
typedef __attribute__((ext_vector_type(4))) unsigned short u16x4;
typedef __attribute__((ext_vector_type(4))) float f32x4;

#define DEV static __device__ __forceinline__
#define MFMA __builtin_amdgcn_mfma_f32_16x16x32_bf16

DEV float bf2f(u16 u) { return __uint_as_float(((unsigned)u) << 16); }
DEV u16 f2bf(float f) {
    unsigned u = __float_as_uint(f);
    return (u16)((u + 0x7FFFu + ((u >> 16) & 1u)) >> 16);
}
DEV void split2(float v, u16& hi, u16& lo) {
    hi = f2bf(v);
    lo = f2bf(v - bf2f(hi));
}

// ===========================================================================
// bf16 hi/lo plane pipeline kernels (verified R5)
// ===========================================================================

// Split fp32 -> bf16 hi/lo planes, elementwise. n multiple of 2048.
__global__ __launch_bounds__(256) void split_k(
    const float* __restrict__ src, u16* __restrict__ dh, u16* __restrict__ dl, long n)
{
    const long i = ((long)blockIdx.x * 256 + threadIdx.x) * 8;
    if (i >= n) return;
    float4 f0 = *(const float4*)(src + i);
    float4 f1 = *(const float4*)(src + i + 4);
    float v[8] = {f0.x, f0.y, f0.z, f0.w, f1.x, f1.y, f1.z, f1.w};
    u16x8 h8, l8;
    for (int j = 0; j < 8; ++j) { u16 hh, ll; split2(v[j], hh, ll); h8[j] = hh; l8[j] = ll; }
    *(u16x8*)(dh + i) = h8;
    *(u16x8*)(dl + i) = l8;
}

// Transpose+split (hi only): src [E][K][N] fp32 -> dst [E][N][K] bf16.
__global__ __launch_bounds__(256) void splitT_k(
    const float* __restrict__ src, u16* __restrict__ dst, int K, int N)
{
    __shared__ u16 tile[64 * 72];
    const int e = blockIdx.z;
    const int n0 = blockIdx.x * 64, k0 = blockIdx.y * 64;
    const long estride = (long)K * N;
    const int tid = threadIdx.x;
    const int tr = tid >> 2, tc = (tid & 3) * 16;
    {
        const float* sp = src + e * estride + (long)(k0 + tr) * N + n0 + tc;
        for (int j = 0; j < 16; j += 4) {
            float4 f = *(const float4*)(sp + j);
            tile[tr * 72 + tc + j + 0] = f2bf(f.x);
            tile[tr * 72 + tc + j + 1] = f2bf(f.y);
            tile[tr * 72 + tc + j + 2] = f2bf(f.z);
            tile[tr * 72 + tc + j + 3] = f2bf(f.w);
        }
    }
    __syncthreads();
    {
        const int tn = tid >> 2, tk = (tid & 3) * 16;
        u16* dp = dst + e * estride + (long)(n0 + tn) * K + k0 + tk;
        u16x8 o0, o1;
        for (int j = 0; j < 8; ++j) {
            o0[j] = tile[(tk + j) * 72 + tn];
            o1[j] = tile[(tk + 8 + j) * 72 + tn];
        }
        *(u16x8*)(dp) = o0;
        *(u16x8*)(dp + 8) = o1;
    }
}

// ---------------------------------------------------------------------------
// GEMM (plane pipeline): C = act(A @ B^T + bias).
// A: fp32 (Af, split in staging) or bf16 planes (Ahp / Alp). a_lo: use lo term.
// B: bf16 planes (Bh required, Bl optional). 3-term split MFMA when both lo.
// Out: fp32 (Cf, optional perm_out scatter) and/or bf16 planes (Ch [+lo at
// clo_off]); plane cols >=512 routed to tensor t=col>>ts at t*tstride.
// ---------------------------------------------------------------------------
__global__ __launch_bounds__(256) void gemm_s(
    const float* __restrict__ Af, const u16* __restrict__ Ahp, const u16* __restrict__ Alp,
    int lda, int a_lo, const int* __restrict__ perm_in,
    const u16* __restrict__ Bh, const u16* __restrict__ Bl, int ldb, long b_estride,
    const int* __restrict__ tile_expert,
    const float* __restrict__ bias, int bias_estride,
    float* __restrict__ Cf, int ldcf, const int* __restrict__ perm_out,
    u16* __restrict__ Ch, long clo_off, int ldcp, int ts, long tstride,
    int K, int act)
{
    __shared__ u16 As[64 * 40], Als[64 * 40];
    __shared__ u16 Bs[64 * 40], Bls[64 * 40];
    const int mt = blockIdx.x, nt = blockIdx.y;
    int e = 0;
    if (tile_expert) { e = tile_expert[mt]; if (e < 0) return; }
    const int tid = threadIdx.x, lane = tid & 63, w = tid >> 6;
    const int wr = (w >> 1) * 32, wc = (w & 1) * 32;
    const int quad = lane >> 4, l15 = lane & 15;
    const int b_lo = (Bl != nullptr);

    const u16* Bhb = Bh + (long)e * b_estride;
    const u16* Blb = b_lo ? (Bl + (long)e * b_estride) : nullptr;

    const int r2 = tid >> 3, c4 = (tid & 7) * 4;   // fp32-A staging
    const int r1 = tid >> 2, c8 = (tid & 3) * 8;   // plane staging
    long arow0 = 0, arow1 = 0, arowb = 0;
    bool v0 = true, v1 = true, vb = true;
    if (perm_in) {
        if (Af) {
            int p0 = perm_in[mt * 64 + r2];      v0 = p0 >= 0; arow0 = p0 < 0 ? 0 : p0;
            int p1 = perm_in[mt * 64 + r2 + 32]; v1 = p1 >= 0; arow1 = p1 < 0 ? 0 : p1;
        } else {
            int pb = perm_in[mt * 64 + r1];      vb = pb >= 0; arowb = pb < 0 ? 0 : pb;
        }
    } else {
        arow0 = (long)mt * 64 + r2; arow1 = arow0 + 32; arowb = (long)mt * 64 + r1;
    }

    f32x4 acc[2][2] = {};

    for (int k0 = 0; k0 < K; k0 += 32) {
        __syncthreads();
        if (Af) {
            for (int half = 0; half < 2; ++half) {
                const int row = half * 32 + r2;
                const long ar = half ? arow1 : arow0;
                const bool va = half ? v1 : v0;
                float4 v = va ? *(const float4*)(Af + ar * (long)lda + k0 + c4)
                              : make_float4(0.f, 0.f, 0.f, 0.f);
                float vv[4] = {v.x, v.y, v.z, v.w};
                u16x4 h4, l4;
                for (int i = 0; i < 4; ++i) { u16 hh, ll; split2(vv[i], hh, ll); h4[i] = hh; l4[i] = ll; }
                *(u16x4*)&As[row * 40 + c4] = h4;
                if (a_lo) *(u16x4*)&Als[row * 40 + c4] = l4;
            }
        } else {
            const long ao = arowb * (long)lda + k0 + c8;
            u16x8 h8 = vb ? *(const u16x8*)(Ahp + ao) : (u16x8)(u16)0;
            *(u16x8*)&As[r1 * 40 + c8] = h8;
            if (a_lo) {
                u16x8 l8 = vb ? *(const u16x8*)(Alp + ao) : (u16x8)(u16)0;
                *(u16x8*)&Als[r1 * 40 + c8] = l8;
            }
        }
        {
            const long bo = ((long)nt * 64 + r1) * ldb + k0 + c8;
            *(u16x8*)&Bs[r1 * 40 + c8] = *(const u16x8*)(Bhb + bo);
            if (b_lo) *(u16x8*)&Bls[r1 * 40 + c8] = *(const u16x8*)(Blb + bo);
        }
        __syncthreads();
        s16x8 ah0 = *(const s16x8*)&As[(wr + l15) * 40 + quad * 8];
        s16x8 ah1 = *(const s16x8*)&As[(wr + 16 + l15) * 40 + quad * 8];
        s16x8 bh0 = *(const s16x8*)&Bs[(wc + l15) * 40 + quad * 8];
        s16x8 bh1 = *(const s16x8*)&Bs[(wc + 16 + l15) * 40 + quad * 8];
        acc[0][0] = MFMA(ah0, bh0, acc[0][0], 0, 0, 0);
        acc[0][1] = MFMA(ah0, bh1, acc[0][1], 0, 0, 0);
        acc[1][0] = MFMA(ah1, bh0, acc[1][0], 0, 0, 0);
        acc[1][1] = MFMA(ah1, bh1, acc[1][1], 0, 0, 0);
        if (a_lo) {
            s16x8 al0 = *(const s16x8*)&Als[(wr + l15) * 40 + quad * 8];
            s16x8 al1 = *(const s16x8*)&Als[(wr + 16 + l15) * 40 + quad * 8];
            acc[0][0] = MFMA(al0, bh0, acc[0][0], 0, 0, 0);
            acc[0][1] = MFMA(al0, bh1, acc[0][1], 0, 0, 0);
            acc[1][0] = MFMA(al1, bh0, acc[1][0], 0, 0, 0);
            acc[1][1] = MFMA(al1, bh1, acc[1][1], 0, 0, 0);
        }
        if (b_lo) {
            s16x8 bl0 = *(const s16x8*)&Bls[(wc + l15) * 40 + quad * 8];
            s16x8 bl1 = *(const s16x8*)&Bls[(wc + 16 + l15) * 40 + quad * 8];
            acc[0][0] = MFMA(ah0, bl0, acc[0][0], 0, 0, 0);
            acc[0][1] = MFMA(ah0, bl1, acc[0][1], 0, 0, 0);
            acc[1][0] = MFMA(ah1, bl0, acc[1][0], 0, 0, 0);
            acc[1][1] = MFMA(ah1, bl1, acc[1][1], 0, 0, 0);
        }
    }

    const float* bp = bias + (long)e * bias_estride;
    for (int mi = 0; mi < 2; ++mi) {
        for (int r = 0; r < 4; ++r) {
            const int rloc = wr + mi * 16 + quad * 4 + r;  // C/D: row=(lane>>4)*4+reg
            const long lrow = (long)mt * 64 + rloc;
            for (int ni = 0; ni < 2; ++ni) {
                const int colg = nt * 64 + wc + ni * 16 + l15;  // C/D: col=lane&15
                float v = acc[mi][ni][r] + bp[colg];
                if (act == 1) v = 0.5f * v * (1.f + erff(v * 0.7071067811865475f));
                if (Cf) {
                    long orow = lrow;
                    if (perm_out) { int po = perm_out[mt * 64 + rloc]; if (po < 0) continue; orow = po; }
                    Cf[orow * (long)ldcf + colg] = v;
                }
                if (Ch) {
                    const int t = colg >> ts;
                    const int cc = colg - (t << ts);
                    const long po = (long)t * tstride + lrow * (long)ldcp + cc;
                    u16 hh, ll; split2(v, hh, ll);
                    Ch[po] = hh;
                    if (clo_off) Ch[po + clo_off] = ll;
                }
            }
        }
    }
}

// ---------------------------------------------------------------------------
// Flash attention on pre-split hi/lo planes. Q/K/V tensors hold Z*2048 rows
// (lo plane at +plo). Block = 64 Q rows of one (z,h); wave = 16 rows;
// 32-key tiles; split-3 MFMA; online softmax in scaled-log2 units.
// O written as planes (lo at +olo) at rows orow_base + z*2048 + ...
// ---------------------------------------------------------------------------
__global__ __launch_bounds__(256) void attn_p(
    const u16* __restrict__ Qh, const u16* __restrict__ Kh, const u16* __restrict__ Vh,
    long plo, u16* __restrict__ Oh, long olo, int orow_base, float sc)
{
    __shared__ u16 Khs[32 * 72], Kls[32 * 72];
    __shared__ u16 Vhs[64 * 40], Vls[64 * 40];
    __shared__ float Ss[4 * 16 * 36];
    const int z = blockIdx.z, h = blockIdx.y, qt = blockIdx.x;
    const int tid = threadIdx.x, lane = tid & 63, w = tid >> 6;
    const int quad = lane >> 4, l15 = lane & 15;

    const long qoff = ((long)z * 2048 + qt * 64 + w * 16 + l15) * 512 + h * 64 + quad * 8;
    s16x8 qh0 = *(const s16x8*)(Qh + qoff);
    s16x8 qh1 = *(const s16x8*)(Qh + qoff + 32);
    s16x8 ql0 = *(const s16x8*)(Qh + plo + qoff);
    s16x8 ql1 = *(const s16x8*)(Qh + plo + qoff + 32);

    const int kr = tid >> 3, kc = (tid & 7) * 8;       // K stage: 32 keys x 64 dims
    const int vkey = tid & 31, vhd0 = (tid >> 5) * 8;  // V stage: transpose

    float m_run = -1e30f, l_run = 0.f;
    f32x4 oacc[4] = {};
    float* Sw = &Ss[w * 16 * 36];

    for (int t = 0; t < 64; ++t) {
        __syncthreads();
        {
            const long ko = ((long)z * 2048 + t * 32 + kr) * 512 + h * 64 + kc;
            *(u16x8*)&Khs[kr * 72 + kc] = *(const u16x8*)(Kh + ko);
            *(u16x8*)&Kls[kr * 72 + kc] = *(const u16x8*)(Kh + plo + ko);
        }
        {
            const long vo = ((long)z * 2048 + t * 32 + vkey) * 512 + h * 64 + vhd0;
            u16x8 vh8 = *(const u16x8*)(Vh + vo);
            u16x8 vl8 = *(const u16x8*)(Vh + plo + vo);
            for (int i = 0; i < 8; ++i) {
                Vhs[(vhd0 + i) * 40 + vkey] = vh8[i];
                Vls[(vhd0 + i) * 40 + vkey] = vl8[i];
            }
        }
        __syncthreads();
        f32x4 s0 = {0.f, 0.f, 0.f, 0.f}, s1 = {0.f, 0.f, 0.f, 0.f};
        {
            s16x8 kh00 = *(const s16x8*)&Khs[l15 * 72 + quad * 8];
            s16x8 kl00 = *(const s16x8*)&Kls[l15 * 72 + quad * 8];
            s16x8 kh01 = *(const s16x8*)&Khs[l15 * 72 + 32 + quad * 8];
            s16x8 kl01 = *(const s16x8*)&Kls[l15 * 72 + 32 + quad * 8];
            s0 = MFMA(qh0, kh00, s0, 0, 0, 0);
            s0 = MFMA(ql0, kh00, s0, 0, 0, 0);
            s0 = MFMA(qh0, kl00, s0, 0, 0, 0);
            s0 = MFMA(qh1, kh01, s0, 0, 0, 0);
            s0 = MFMA(ql1, kh01, s0, 0, 0, 0);
            s0 = MFMA(qh1, kl01, s0, 0, 0, 0);
            s16x8 kh10 = *(const s16x8*)&Khs[(16 + l15) * 72 + quad * 8];
            s16x8 kl10 = *(const s16x8*)&Kls[(16 + l15) * 72 + quad * 8];
            s16x8 kh11 = *(const s16x8*)&Khs[(16 + l15) * 72 + 32 + quad * 8];
            s16x8 kl11 = *(const s16x8*)&Kls[(16 + l15) * 72 + 32 + quad * 8];
            s1 = MFMA(qh0, kh10, s1, 0, 0, 0);
            s1 = MFMA(ql0, kh10, s1, 0, 0, 0);
            s1 = MFMA(qh0, kl10, s1, 0, 0, 0);
            s1 = MFMA(qh1, kh11, s1, 0, 0, 0);
            s1 = MFMA(ql1, kh11, s1, 0, 0, 0);
            s1 = MFMA(qh1, kl11, s1, 0, 0, 0);
        }
        for (int r = 0; r < 4; ++r) {
            Sw[(quad * 4 + r) * 36 + l15]      = s0[r];
            Sw[(quad * 4 + r) * 36 + 16 + l15] = s1[r];
        }
        __syncthreads();
        float p[8]; float lm = -1e30f;
        const float* srow = &Sw[l15 * 36 + quad * 8];
        for (int j = 0; j < 8; ++j) { p[j] = srow[j] * sc; lm = fmaxf(lm, p[j]); }
        lm = fmaxf(lm, __shfl_xor(lm, 16));
        lm = fmaxf(lm, __shfl_xor(lm, 32));
        const float m_new = fmaxf(m_run, lm);
        const float alpha = exp2f(m_run - m_new);
        float ts = 0.f;
        for (int j = 0; j < 8; ++j) { p[j] = exp2f(p[j] - m_new); ts += p[j]; }
        ts += __shfl_xor(ts, 16);
        ts += __shfl_xor(ts, 32);
        l_run = l_run * alpha + ts;
        m_run = m_new;
        s16x8 ph, pl;
        for (int j = 0; j < 8; ++j) {
            u16 hh, ll; split2(p[j], hh, ll);
            ph[j] = (short)hh; pl[j] = (short)ll;
        }
        float ar[4];
        for (int r = 0; r < 4; ++r) ar[r] = __shfl(alpha, quad * 4 + r);
        for (int tt = 0; tt < 4; ++tt) {
            f32x4 oa = oacc[tt];
            oa[0] *= ar[0]; oa[1] *= ar[1]; oa[2] *= ar[2]; oa[3] *= ar[3];
            s16x8 vh = *(const s16x8*)&Vhs[(tt * 16 + l15) * 40 + quad * 8];
            s16x8 vl = *(const s16x8*)&Vls[(tt * 16 + l15) * 40 + quad * 8];
            oa = MFMA(ph, vh, oa, 0, 0, 0);
            oa = MFMA(pl, vh, oa, 0, 0, 0);
            oa = MFMA(ph, vl, oa, 0, 0, 0);
            oacc[tt] = oa;
        }
    }
    float linv[4];
    for (int r = 0; r < 4; ++r) linv[r] = 1.f / fmaxf(__shfl(l_run, quad * 4 + r), 1e-35f);
    const long obase = ((long)orow_base + z * 2048 + qt * 64 + w * 16 + quad * 4) * 512 + h * 64;
    for (int tt = 0; tt < 4; ++tt)
        for (int r = 0; r < 4; ++r) {
            u16 hh, ll; split2(oacc[tt][r] * linv[r], hh, ll);
            const long oo = obase + (long)r * 512 + tt * 16 + l15;
            Oh[oo] = hh;
            Oh[olo + oo] = ll;
        }
}

// ---------------------------------------------------------------------------
// Residual + LayerNorm (D=512). a/b each either fp32 or hi/lo planes.
// Output fp32 and/or planes.
// ---------------------------------------------------------------------------
__global__ __launch_bounds__(256) void ln_p(
    const float* __restrict__ af, const u16* __restrict__ ah, long alo,
    const float* __restrict__ bf, const u16* __restrict__ bh, long blo,
    const float* __restrict__ g, const float* __restrict__ be,
    float* __restrict__ of, u16* __restrict__ oh, long olo)
{
    const int tid = threadIdx.x, lane = tid & 63, w = tid >> 6;
    const long base = ((long)blockIdx.x * 4 + w) * 512 + lane * 8;
    float v[8];
    if (af) {
        float4 f0 = *(const float4*)(af + base);
        float4 f1 = *(const float4*)(af + base + 4);
        v[0] = f0.x; v[1] = f0.y; v[2] = f0.z; v[3] = f0.w;
        v[4] = f1.x; v[5] = f1.y; v[6] = f1.z; v[7] = f1.w;
    } else {
        u16x8 hh = *(const u16x8*)(ah + base);
        u16x8 ll = *(const u16x8*)(ah + alo + base);
        for (int j = 0; j < 8; ++j) v[j] = bf2f(hh[j]) + bf2f(ll[j]);
    }
    if (bf) {
        float4 f0 = *(const float4*)(bf + base);
        float4 f1 = *(const float4*)(bf + base + 4);
        v[0] += f0.x; v[1] += f0.y; v[2] += f0.z; v[3] += f0.w;
        v[4] += f1.x; v[5] += f1.y; v[6] += f1.z; v[7] += f1.w;
    } else {
        u16x8 hh = *(const u16x8*)(bh + base);
        u16x8 ll = *(const u16x8*)(bh + blo + base);
        for (int j = 0; j < 8; ++j) v[j] += bf2f(hh[j]) + bf2f(ll[j]);
    }
    float s = 0.f, sq = 0.f;
    for (int j = 0; j < 8; ++j) { s += v[j]; sq += v[j] * v[j]; }
    for (int m = 1; m < 64; m <<= 1) { s += __shfl_xor(s, m); sq += __shfl_xor(sq, m); }
    const float mu = s * (1.f / 512.f);
    const float var = fmaxf(sq * (1.f / 512.f) - mu * mu, 0.f);
    const float rs = rsqrtf(var + 1e-5f);
    float4 ga = *(const float4*)(g + lane * 8);
    float4 gb = *(const float4*)(g + lane * 8 + 4);
    float4 ba = *(const float4*)(be + lane * 8);
    float4 bb = *(const float4*)(be + lane * 8 + 4);
    float gg[8] = {ga.x, ga.y, ga.z, ga.w, gb.x, gb.y, gb.z, gb.w};
    float bv[8] = {ba.x, ba.y, ba.z, ba.w, bb.x, bb.y, bb.z, bb.w};
    float o[8];
    for (int j = 0; j < 8; ++j) o[j] = (v[j] - mu) * rs * gg[j] + bv[j];
    if (of) {
        *(float4*)(of + base)     = make_float4(o[0], o[1], o[2], o[3]);
        *(float4*)(of + base + 4) = make_float4(o[4], o[5], o[6], o[7]);
    }
    if (oh) {
        u16x8 h8, l8;
        for (int j = 0; j < 8; ++j) { u16 hh, ll; split2(o[j], hh, ll); h8[j] = hh; l8[j] = ll; }
        *(u16x8*)(oh + base) = h8;
        *(u16x8*)(oh + olo + base) = l8;
    }
}

// Routing from hi/lo planes (argmax of logits). One wave per token.
__global__ __launch_bounds__(256) void route_p(
    const u16* __restrict__ xh, long xlo,
    const float* __restrict__ gw, const float* __restrict__ gb,
    int* __restrict__ idx, int* __restrict__ counts)
{
    const int tid = threadIdx.x, lane = tid & 63, w = tid >> 6;
    const long row = (long)blockIdx.x * 4 + w;
    const long base = row * 512 + lane * 8;
    u16x8 hh = *(const u16x8*)(xh + base);
    u16x8 ll = *(const u16x8*)(xh + xlo + base);
    float xf[8];
    for (int j = 0; j < 8; ++j) xf[j] = bf2f(hh[j]) + bf2f(ll[j]);
    float best = -1e30f; int bi = 0;
    for (int e = 0; e < 4; ++e) {
        float4 w0 = *(const float4*)(gw + e * 512 + lane * 8);
        float4 w1 = *(const float4*)(gw + e * 512 + lane * 8 + 4);
        float wf[8] = {w0.x, w0.y, w0.z, w0.w, w1.x, w1.y, w1.z, w1.w};
        float d = 0.f;
        for (int j = 0; j < 8; ++j) d += xf[j] * wf[j];
        for (int m = 1; m < 64; m <<= 1) d += __shfl_xor(d, m);
        d += gb[e];
        if (d > best) { best = d; bi = e; }
    }
    if (lane == 0) { idx[row] = bi; atomicAdd(&counts[bi], 1); }
}

__global__ void plan_k(const int* __restrict__ counts, int* __restrict__ cursors,
                       int* __restrict__ tile_expert)
{
    if (threadIdx.x != 0 || blockIdx.x != 0) return;
    int off = 0;
    for (int e = 0; e < 4; ++e) {
        cursors[e] = off;
        int nt = (counts[e] + 63) >> 6;
        int t0 = off >> 6;
        for (int i = 0; i < nt; ++i) tile_expert[t0 + i] = e;
        off += nt << 6;
    }
    for (int t = off >> 6; t < 132; ++t) tile_expert[t] = -1;
}

__global__ __launch_bounds__(256) void scatter_k(
    const int* __restrict__ idx, int* __restrict__ cursors, int* __restrict__ perm)
{
    const int t = blockIdx.x * 256 + threadIdx.x;
    const int e = idx[t];
    const int pos = atomicAdd(&cursors[e], 1);
    perm[pos] = t;
}

// ===========================================================================
extern "C" void kernel_launch(void* const* d_in, const int* in_sizes, int n_in,
                              void* d_out, int out_size, void* d_ws, size_t ws_size,
                              hipStream_t stream)
{
    (void)in_sizes; (void)n_in; (void)out_size;
    const float* x        = (const float*)d_in[0];
    const float* mem      = (const float*)d_in[1];
    const float* sa_in_w  = (const float*)d_in[2];
    const float* sa_in_b  = (const float*)d_in[3];
    const float* sa_out_w = (const float*)d_in[4];
    const float* sa_out_b = (const float*)d_in[5];
    const float* ca_in_w  = (const float*)d_in[6];
    const float* ca_in_b  = (const float*)d_in[7];
    const float* ca_out_w = (const float*)d_in[8];
    const float* ca_out_b = (const float*)d_in[9];
    const float* gate_w   = (const float*)d_in[10];
    const float* gate_b   = (const float*)d_in[11];
    const float* w1       = (const float*)d_in[12];
    const float* b1       = (const float*)d_in[13];
    const float* w2       = (const float*)d_in[14];
    const float* b2       = (const float*)d_in[15];
    const float* ln1_g    = (const float*)d_in[16];
    const float* ln1_b    = (const float*)d_in[17];
    const float* ln2_g    = (const float*)d_in[18];
    const float* ln2_b    = (const float*)d_in[19];
    const float* ln3_g    = (const float*)d_in[20];
    const float* ln3_b    = (const float*)d_in[21];

    const float sc = 0.125f * 1.4426950408889634f;
    dim3 blk(256, 1, 1);
    char* ws = (char*)d_ws;

    // attn weight plane offsets (elements within WA)
    const long WAe_sa_in = 0, WAe_sa_out = 1572864, WAe_ca_in = 2097152, WAe_ca_out = 3670016;

    const size_t BIG_NEED  = 109119104;  // 4-batch QKV plan
    const size_t FAST_NEED = 100730416;  // proven R5 plan (ws >= this is measured)

    if (ws_size >= BIG_NEED) {
        // -------- BIG: 4-batch QKV, single attn dispatch per phase --------
        // byte offsets:
        // 0           WA attn weight planes             ( 8,388,608)
        // 8,388,608   QKVp: Q,K,V plane tensors 4-batch (50,331,648)  -> MoE H (34.6MB)
        // 58,720,256  Op planes                         (16,777,216)  -> ymoe fp32
        // 75,497,472  P1p planes                        (16,777,216)  -> w1h+w2h
        // 92,274,688  X1p/X2p planes                    (16,777,216)
        // 109,051,904 meta
        u16* WA   = (u16*)(ws);
        u16* QKVp = (u16*)(ws + 8388608L);
        u16* Op   = (u16*)(ws + 58720256L);
        float* ymoe = (float*)(ws + 58720256L);
        u16* P1p  = (u16*)(ws + 75497472L);
        u16* X1p  = (u16*)(ws + 92274688L);
        int* idx    = (int*)(ws + 109051904L);
        int* perm   = (int*)(ws + 109051904L + 32768);
        int* counts = (int*)(ws + 109051904L + 32768 + 33792);
        int* cursors= (int*)(ws + 109051904L + 32768 + 33792 + 16);
        int* tile_e = (int*)(ws + 109051904L + 32768 + 33792 + 32);

        const long L = 4194304;   // lo-plane offset, 8192x512 tensor (elements)
        const long T = 8388608;   // tensor stride (hi+lo), elements

        hipMemsetAsync(counts, 0, 16, stream);
        hipMemsetAsync(perm, 0xFF, 8448 * 4, stream);

        // attn weight splits
        split_k<<<dim3(384), blk, 0, stream>>>(sa_in_w,  WA + WAe_sa_in,  WA + WAe_sa_in + 786432, 786432);
        split_k<<<dim3(128), blk, 0, stream>>>(sa_out_w, WA + WAe_sa_out, WA + WAe_sa_out + 262144, 262144);
        split_k<<<dim3(384), blk, 0, stream>>>(ca_in_w,  WA + WAe_ca_in,  WA + WAe_ca_in + 786432, 786432);
        split_k<<<dim3(128), blk, 0, stream>>>(ca_out_w, WA + WAe_ca_out, WA + WAe_ca_out + 262144, 262144);

        // ---- self attention ----
        gemm_s<<<dim3(128, 24), blk, 0, stream>>>(
            x, nullptr, nullptr, 512, 1, nullptr,
            WA + WAe_sa_in, WA + WAe_sa_in + 786432, 512, 0, nullptr,
            sa_in_b, 0, nullptr, 0, nullptr,
            QKVp, L, 512, 9, T, 512, 0);
        attn_p<<<dim3(32, 8, 4), blk, 0, stream>>>(
            QKVp, QKVp + T, QKVp + 2 * T, L, Op, L, 0, sc);
        gemm_s<<<dim3(128, 8), blk, 0, stream>>>(
            nullptr, Op, Op + L, 512, 1, nullptr,
            WA + WAe_sa_out, WA + WAe_sa_out + 262144, 512, 0, nullptr,
            sa_out_b, 0, nullptr, 0, nullptr,
            P1p, L, 512, 9, 0, 512, 0);
        ln_p<<<dim3(2048), blk, 0, stream>>>(x, nullptr, 0, nullptr, P1p, L,
                                             ln1_g, ln1_b, nullptr, X1p, L);

        // ---- cross attention ----
        gemm_s<<<dim3(128, 8), blk, 0, stream>>>(
            nullptr, X1p, X1p + L, 512, 1, nullptr,
            WA + WAe_ca_in, WA + WAe_ca_in + 786432, 512, 0, nullptr,
            ca_in_b, 0, nullptr, 0, nullptr,
            QKVp, L, 512, 9, T, 512, 0);                    // Q -> tensor 0
        gemm_s<<<dim3(128, 16), blk, 0, stream>>>(
            mem, nullptr, nullptr, 512, 1, nullptr,
            WA + WAe_ca_in + 262144, WA + WAe_ca_in + 786432 + 262144, 512, 0, nullptr,
            ca_in_b + 512, 0, nullptr, 0, nullptr,
            QKVp + T, L, 512, 9, T, 512, 0);                // K,V -> tensors 1,2
        attn_p<<<dim3(32, 8, 4), blk, 0, stream>>>(
            QKVp, QKVp + T, QKVp + 2 * T, L, Op, L, 0, sc);
        gemm_s<<<dim3(128, 8), blk, 0, stream>>>(
            nullptr, Op, Op + L, 512, 1, nullptr,
            WA + WAe_ca_out, WA + WAe_ca_out + 262144, 512, 0, nullptr,
            ca_out_b, 0, nullptr, 0, nullptr,
            P1p, L, 512, 9, 0, 512, 0);
        ln_p<<<dim3(2048), blk, 0, stream>>>(nullptr, X1p, L, nullptr, P1p, L,
                                             ln2_g, ln2_b, nullptr, X1p, L);  // X2p in-place

        // ---- MoE (top-1, grouped; single pass, H in QKVp, w1h/w2h in P1p) ----
        route_p<<<dim3(2048), blk, 0, stream>>>(X1p, L, gate_w, gate_b, idx, counts);
        plan_k<<<dim3(1), dim3(64), 0, stream>>>(counts, cursors, tile_e);
        scatter_k<<<dim3(32), blk, 0, stream>>>(idx, cursors, perm);
        splitT_k<<<dim3(32, 8, 4), blk, 0, stream>>>(w1, P1p, 512, 2048);           // w1h [E][2048][512]
        splitT_k<<<dim3(8, 32, 4), blk, 0, stream>>>(w2, P1p + 4194304, 2048, 512); // w2h [E][512][2048]
        gemm_s<<<dim3(132, 32), blk, 0, stream>>>(
            nullptr, X1p, nullptr, 512, 0, perm,
            P1p, nullptr, 512, 1048576, tile_e,
            b1, 2048, nullptr, 0, nullptr,
            QKVp, 0, 2048, 31, 0, 512, 1);
        gemm_s<<<dim3(132, 8), blk, 0, stream>>>(
            nullptr, QKVp, nullptr, 2048, 0, nullptr,
            P1p + 4194304, nullptr, 2048, 1048576, tile_e,
            b2, 512, ymoe, 512, perm,
            nullptr, 0, 0, 31, 0, 2048, 0);
        ln_p<<<dim3(2048), blk, 0, stream>>>(nullptr, X1p, L, ymoe, nullptr, 0,
                                             ln3_g, ln3_b, (float*)d_out, nullptr, 0);
    } else {
        // -------- proven R5 plan (ws >= 100.7 MB measured) --------
        u16* WA   = (u16*)(ws);
        u16* w1h  = (u16*)(ws + 8388608L);
        u16* w2h  = (u16*)(ws + 16777216L);
        u16* QKVp = (u16*)(ws + 25165824L);
        u16* Op   = (u16*)(ws + 50331648L);
        u16* P1p  = (u16*)(ws + 67108864L);
        float* ymoe = (float*)(ws + 67108864L);
        u16* X1p  = (u16*)(ws + 83886080L);
        int* idx    = (int*)(ws + 100663296L);
        int* perm   = (int*)(ws + 100663296L + 32768);
        int* counts = (int*)(ws + 100663296L + 32768 + 33792);
        int* cursors= (int*)(ws + 100663296L + 32768 + 33792 + 16);
        int* tile_e = (int*)(ws + 100663296L + 32768 + 33792 + 32);

        const long L_QKV = 2097152, T_QKV = 4194304, L_8K = 4194304;
        const long SL = 1048576;

        hipMemsetAsync(counts, 0, 16, stream);
        hipMemsetAsync(perm, 0xFF, 8448 * 4, stream);

        split_k<<<dim3(384), blk, 0, stream>>>(sa_in_w,  WA + WAe_sa_in,  WA + WAe_sa_in + 786432, 786432);
        split_k<<<dim3(128), blk, 0, stream>>>(sa_out_w, WA + WAe_sa_out, WA + WAe_sa_out + 262144, 262144);
        split_k<<<dim3(384), blk, 0, stream>>>(ca_in_w,  WA + WAe_ca_in,  WA + WAe_ca_in + 786432, 786432);
        split_k<<<dim3(128), blk, 0, stream>>>(ca_out_w, WA + WAe_ca_out, WA + WAe_ca_out + 262144, 262144);
        splitT_k<<<dim3(32, 8, 4), blk, 0, stream>>>(w1, w1h, 512, 2048);
        splitT_k<<<dim3(8, 32, 4), blk, 0, stream>>>(w2, w2h, 2048, 512);

        for (int hB = 0; hB < 2; ++hB) {
            gemm_s<<<dim3(64, 24), blk, 0, stream>>>(
                x + hB * 2 * SL, nullptr, nullptr, 512, 1, nullptr,
                WA + WAe_sa_in, WA + WAe_sa_in + 786432, 512, 0, nullptr,
                sa_in_b, 0, nullptr, 0, nullptr,
                QKVp, L_QKV, 512, 9, T_QKV, 512, 0);
            attn_p<<<dim3(32, 8, 2), blk, 0, stream>>>(
                QKVp, QKVp + T_QKV, QKVp + 2 * T_QKV, L_QKV, Op, L_8K, hB * 4096, sc);
        }
        gemm_s<<<dim3(128, 8), blk, 0, stream>>>(
            nullptr, Op, Op + L_8K, 512, 1, nullptr,
            WA + WAe_sa_out, WA + WAe_sa_out + 262144, 512, 0, nullptr,
            sa_out_b, 0, nullptr, 0, nullptr,
            P1p, L_8K, 512, 9, 0, 512, 0);
        ln_p<<<dim3(2048), blk, 0, stream>>>(x, nullptr, 0, nullptr, P1p, L_8K,
                                             ln1_g, ln1_b, nullptr, X1p, L_8K);

        for (int hB = 0; hB < 2; ++hB) {
            gemm_s<<<dim3(64, 8), blk, 0, stream>>>(
                nullptr, X1p + hB * L_QKV, X1p + L_8K + hB * L_QKV, 512, 1, nullptr,
                WA + WAe_ca_in, WA + WAe_ca_in + 786432, 512, 0, nullptr,
                ca_in_b, 0, nullptr, 0, nullptr,
                QKVp, L_QKV, 512, 9, T_QKV, 512, 0);
            gemm_s<<<dim3(64, 16), blk, 0, stream>>>(
                mem + hB * 2 * SL, nullptr, nullptr, 512, 1, nullptr,
                WA + WAe_ca_in + 262144, WA + WAe_ca_in + 786432 + 262144, 512, 0, nullptr,
                ca_in_b + 512, 0, nullptr, 0, nullptr,
                QKVp + T_QKV, L_QKV, 512, 9, T_QKV, 512, 0);
            attn_p<<<dim3(32, 8, 2), blk, 0, stream>>>(
                QKVp, QKVp + T_QKV, QKVp + 2 * T_QKV, L_QKV, Op, L_8K, hB * 4096, sc);
        }
        gemm_s<<<dim3(128, 8), blk, 0, stream>>>(
            nullptr, Op, Op + L_8K, 512, 1, nullptr,
            WA + WAe_ca_out, WA + WAe_ca_out + 262144, 512, 0, nullptr,
            ca_out_b, 0, nullptr, 0, nullptr,
            P1p, L_8K, 512, 9, 0, 512, 0);
        ln_p<<<dim3(2048), blk, 0, stream>>>(nullptr, X1p, L_8K, nullptr, P1p, L_8K,
                                             ln2_g, ln2_b, nullptr, X1p, L_8K);

        route_p<<<dim3(2048), blk, 0, stream>>>(X1p, L_8K, gate_w, gate_b, idx, counts);
        plan_k<<<dim3(1), dim3(64), 0, stream>>>(counts, cursors, tile_e);
        scatter_k<<<dim3(32), blk, 0, stream>>>(idx, cursors, perm);
        for (int c = 0; c < 2; ++c) {
            const int t0 = c * 66;
            gemm_s<<<dim3(66, 32), blk, 0, stream>>>(
                nullptr, X1p, nullptr, 512, 0, perm + t0 * 64,
                w1h, nullptr, 512, 1048576, tile_e + t0,
                b1, 2048, nullptr, 0, nullptr,
                QKVp, 0, 2048, 31, 0, 512, 1);
            gemm_s<<<dim3(66, 8), blk, 0, stream>>>(
                nullptr, QKVp, nullptr, 2048, 0, nullptr,
                w2h, nullptr, 2048, 1048576, tile_e + t0,
                b2, 512, ymoe, 512, perm + t0 * 64,
                nullptr, 0, 0, 31, 0, 2048, 0);
        }
        ln_p<<<dim3(2048), blk, 0, stream>>>(nullptr, X1p, L_8K, ymoe, nullptr, 0,
                                             ln3_g, ln3_b, (float*)d_out, nullptr, 0);
    }
}